// Round 3
// baseline (441.159 us; speedup 1.0000x reference)
//
#include <hip/hip_runtime.h>
#include <hip/hip_bf16.h>

// Problem constants
#define Bq 16
#define Nq 256
#define E1q 4
#define Hq 8
#define Dq 128
#define EH 32
#define BN 4096

typedef __hip_bfloat16 bf16;
typedef short bf16x8 __attribute__((ext_vector_type(8)));
typedef float f32x4 __attribute__((ext_vector_type(4)));

__device__ __forceinline__ void gll16(const void* gptr, void* lptr) {
    __builtin_amdgcn_global_load_lds(
        (const __attribute__((address_space(1))) void*)gptr,
        (__attribute__((address_space(3))) void*)lptr, 16, 0, 0);
}

__device__ __forceinline__ unsigned short f2bf(float v) {
    __hip_bfloat16 h = __float2bfloat16(v);
    return *(unsigned short*)&h;
}

// ---------------------------------------------------------------------------
// K0: fused prep: gather st0b | transpose W0 | transpose W1 | pack Le
__device__ __forceinline__ void transpose_tile(const float* __restrict__ W,
                                               bf16* __restrict__ WT, int K,
                                               int kt, int nt, int eh,
                                               float (*tile)[65], int tid) {
    int tr = tid >> 6, tc = tid & 63;
    const float* src = W + ((size_t)eh * K + kt * 64) * 128 + nt * 64;
#pragma unroll
    for (int p = 0; p < 16; ++p) {
        int r = p * 4 + tr;
        tile[r][tc] = src[(size_t)r * 128 + tc];
    }
    __syncthreads();
    bf16* dst = WT + ((size_t)eh * 128 + nt * 64) * K + kt * 64;
#pragma unroll
    for (int p = 0; p < 16; ++p) {
        int n = p * 4 + tr;
        dst[(size_t)n * K + tc] = __float2bfloat16(tile[tc][n]);
    }
}

__global__ __launch_bounds__(256) void prep_kernel(const int* __restrict__ nf,
                                                   const float* __restrict__ emb,
                                                   const float* __restrict__ W0,
                                                   const float* __restrict__ W1,
                                                   const float* __restrict__ L,
                                                   bf16* __restrict__ st0b,
                                                   bf16* __restrict__ W0T,
                                                   bf16* __restrict__ W1T,
                                                   float* __restrict__ Le) {
    int bid = blockIdx.x;
    int t = threadIdx.x;
    __shared__ float tile[64][65];
    if (bid < 2048) {
        int i = bid * 256 + t;
        int row = i >> 7, col = i & 127;
        st0b[i] = __float2bfloat16(emb[nf[row] * Dq + col]);
    } else if (bid < 2176) {
        int id2 = bid - 2048;                       // (2 kt, 2 nt, 32 eh)
        transpose_tile(W0, W0T, 128, id2 & 1, (id2 >> 1) & 1, id2 >> 2, tile, t);
    } else if (bid < 6272) {
        int id3 = bid - 2176;                       // (64 kt, 2 nt, 32 eh)
        transpose_tile(W1, W1T, 4096, id3 & 63, (id3 >> 6) & 1, id3 >> 7, tile, t);
    } else {
        int idx = (bid - 6272) * 256 + t;           // 0..1048575
        float4 v = *(const float4*)(L + (size_t)idx * 4);
        Le[idx] = v.x;
        Le[1048576 + idx] = v.y;
        Le[2097152 + idx] = v.z;
        Le[3145728 + idx] = v.w;
    }
}

// ---------------------------------------------------------------------------
// K4: bf16 MFMA GEMM — LAYER 0 ONLY (K=128), 128-tile 2-barrier structure.
__global__ __launch_bounds__(256) void mfma_gemm_kernel(const bf16* __restrict__ Ab,
                                                        const bf16* __restrict__ Bt,
                                                        bf16* __restrict__ Wht,
                                                        const float* __restrict__ a1w,
                                                        const float* __restrict__ a1b,
                                                        const float* __restrict__ a2w,
                                                        const float* __restrict__ a2b,
                                                        float* __restrict__ s1,
                                                        float* __restrict__ s2, int K) {
    int id = blockIdx.x;
    int xcd = id & 7, slot = id >> 3;
    int eh = (slot & 3) * 8 + xcd;
    int rt = slot >> 2;
    int tid = threadIdx.x;
    int w = tid >> 6, l = tid & 63;
    int q = l >> 4, mn = l & 15;
    __shared__ __align__(16) bf16 As[128 * 64];
    __shared__ __align__(16) bf16 Bs[128 * 64];
    __shared__ float red1[128], red2[128];
    const bf16* Ap = Ab + (size_t)(rt * 128) * K;
    const bf16* Bp = Bt + (size_t)eh * 128 * K;
    int lr = l >> 3;                      // local row within 8-row chunk
    int g = (l & 7) ^ lr;                 // swizzled global k-quad for staging
    int gcol = g * 8;

    if (tid < 128) { red1[tid] = 0.f; red2[tid] = 0.f; }

    f32x4 acc[4][4];
#pragma unroll
    for (int i = 0; i < 4; i++)
#pragma unroll
        for (int j = 0; j < 4; j++) acc[i][j] = (f32x4){0.f, 0.f, 0.f, 0.f};

    int wr = (w >> 1) * 64, wc = (w & 1) * 64;
    int msw = mn & 7;

    for (int k0 = 0; k0 < K; k0 += 64) {
#pragma unroll
        for (int u = 0; u < 4; ++u) {
            int i = w * 4 + u;            // chunk 0..15
            int r = i * 8 + lr;
            gll16(Ap + (size_t)r * K + k0 + gcol, (char*)As + i * 1024);
            gll16(Bp + (size_t)r * K + k0 + gcol, (char*)Bs + i * 1024);
        }
        __syncthreads();
#pragma unroll
        for (int kk = 0; kk < 2; ++kk) {
            int qb = ((kk * 4 + q) ^ msw) * 16;
            bf16x8 af[4], bfr[4];
#pragma unroll
            for (int i = 0; i < 4; ++i) {
                af[i]  = *(const bf16x8*)((const char*)As + (wr + i * 16 + mn) * 128 + qb);
                bfr[i] = *(const bf16x8*)((const char*)Bs + (wc + i * 16 + mn) * 128 + qb);
            }
#pragma unroll
            for (int i = 0; i < 4; ++i)
#pragma unroll
                for (int j = 0; j < 4; ++j)
                    acc[i][j] = __builtin_amdgcn_mfma_f32_16x16x32_bf16(af[i], bfr[j], acc[i][j], 0, 0, 0);
        }
        __syncthreads();
    }
    // transposed bf16 store
#pragma unroll
    for (int i = 0; i < 4; ++i) {
        int r0 = rt * 128 + wr + i * 16 + q * 4;
        int b = r0 >> 8, m = r0 & 255;
#pragma unroll
        for (int j = 0; j < 4; ++j) {
            int o = wc + j * 16 + mn;
            ushort4 pk;
            pk.x = f2bf(acc[i][j][0]);
            pk.y = f2bf(acc[i][j][1]);
            pk.z = f2bf(acc[i][j][2]);
            pk.w = f2bf(acc[i][j][3]);
            *(ushort4*)(Wht + ((((size_t)eh * 16 + b) * 128 + o) * 256 + m)) = pk;
        }
    }
    // fused s1/s2
    float w1v[4], w2v[4];
#pragma unroll
    for (int j = 0; j < 4; ++j) {
        int o = wc + j * 16 + mn;
        w1v[j] = a1w[eh * 128 + o];
        w2v[j] = a2w[eh * 128 + o];
    }
#pragma unroll
    for (int i = 0; i < 4; ++i)
#pragma unroll
        for (int r = 0; r < 4; ++r) {
            float p1 = 0.f, p2 = 0.f;
#pragma unroll
            for (int j = 0; j < 4; ++j) {
                p1 += acc[i][j][r] * w1v[j];
                p2 += acc[i][j][r] * w2v[j];
            }
#pragma unroll
            for (int off = 1; off < 16; off <<= 1) {
                p1 += __shfl_xor(p1, off);
                p2 += __shfl_xor(p2, off);
            }
            if (mn == 0) {
                int row = wr + i * 16 + q * 4 + r;
                atomicAdd(&red1[row], p1);
                atomicAdd(&red2[row], p2);
            }
        }
    __syncthreads();
    if (tid < 128) {
        int rg = rt * 128 + tid;
        s1[eh * 4096 + rg] = red1[tid] + a1b[eh];
        s2[eh * 4096 + rg] = red2[tid] + a2b[eh];
    }
}

// ---------------------------------------------------------------------------
// K4b: LAYER-1 GEMM (4096^3 bf16), 256x256 tile, register software pipeline.
// 512 thr / 8 waves (2Mx4N), per-wave 128x64 out, acc[8][4].
// BK=32, 4-deep LDS ring, 3-tile staging prefetch.
// KEY (R2 post-mortem): lgkm waits must target PREVIOUS-tile reads, not
// same-tile reads, or MFMA and the LDS drain serialize (1242+1152 cyc/tile,
// MfmaUtil 42 -> 37 in R1/R2). So iter t reads tile t+1's fragments while
// MFMA'ing tile t's (read during t-1): the 96 ds_reads/CU drain UNDER the
// 32-MFMA cluster. One barrier / one lgkm(8) / one vmcnt(4) per K-tile.
// Ledger: stages in flight at vmcnt = {t+2,t+3} = 8 gll -> vmcnt(4) => t+2
// resident for iter t+1's reads. stage(t+3) overwrites buf (t-1)&3 whose
// reads finished at iter t-2, two barriers back. Tail: vmcnt(0)@125,
// lgkm(0)@127, reads guarded t<127, stages t<125.
__global__ __launch_bounds__(512, 2) void gemm4k_kernel(const bf16* __restrict__ Ab,
                                                        const bf16* __restrict__ Bt,
                                                        bf16* __restrict__ Wht,
                                                        const float* __restrict__ a1w,
                                                        const float* __restrict__ a1b,
                                                        const float* __restrict__ a2w,
                                                        const float* __restrict__ a2b,
                                                        float* __restrict__ s1,
                                                        float* __restrict__ s2) {
    __shared__ __align__(16) char smem[131072];     // [0,64K): A ring, [64K,128K): B ring
    int bid = blockIdx.x;
    int wg = (bid & 7) * 32 + (bid >> 3);           // XCD-bijective (256 % 8 == 0)
    int tm = wg >> 4, tn = wg & 15;                 // tm: batch/row tile, tn: eh-pair
    int tid = threadIdx.x;
    int wid = tid >> 6, l = tid & 63;
    int wr = wid >> 2, wc = wid & 3;                // wave 2M x 4N
    int lhi = l >> 4, llo = l & 15;
    int sa = (lhi ^ ((l >> 1) & 3)) << 4;           // read-side swizzled 16B slot
    int skq = (l & 3) ^ ((l >> 3) & 3);             // stage-side pre-swizzled k-quad

    const bf16* Ap = Ab + (size_t)tm * 256 * 4096;
    const bf16* Bp = Bt + (size_t)tn * 256 * 4096;
    const bf16* sA = Ap + (size_t)(wid * 16 + (l >> 2)) * 4096 + skq * 8;
    const bf16* sB = Bp + (size_t)(wid * 16 + (l >> 2)) * 4096 + skq * 8;
    char* dA = (char*)smem + wid * 1024;            // wave-uniform LDS dests
    char* dB = (char*)smem + 65536 + wid * 1024;

    auto stageA = [&](int tt) {
        int bo = (tt & 3) * 16384;
        gll16(sA + tt * 32, dA + bo);
        gll16(sA + (size_t)128 * 4096 + tt * 32, dA + bo + 8192);
    };
    auto stageB = [&](int tt) {
        int bo = (tt & 3) * 16384;
        gll16(sB + tt * 32, dB + bo);
        gll16(sB + (size_t)128 * 4096 + tt * 32, dB + bo + 8192);
    };

    f32x4 acc[8][4];
#pragma unroll
    for (int i = 0; i < 8; ++i)
#pragma unroll
        for (int j = 0; j < 4; ++j) acc[i][j] = (f32x4){0.f, 0.f, 0.f, 0.f};

    // read byte offsets (A rows: mh*128 + wr*64 + m*16 + llo; B cols likewise)
    int aoff = ((wr * 64 + llo) << 6) + sa;         // + buf*16384 + mh*8192 + m*1024
    int boff[4];
#pragma unroll
    for (int n = 0; n < 4; ++n)
        boff[n] = 65536 + (((n >> 1) * 128 + wc * 32 + (n & 1) * 16 + llo) << 6) + sa;

    // prologue: tiles 0,1,2 staged; tiles 0,1 resident; preload tile-0 frags
    stageA(0); stageB(0); stageA(1); stageB(1); stageA(2); stageB(2);
    asm volatile("s_waitcnt vmcnt(4)" ::: "memory");
    __builtin_amdgcn_s_barrier();
    const char* sm = (const char*)smem;
    bf16x8 cb[4], ca0[4], ca1[4];
#pragma unroll
    for (int n = 0; n < 4; ++n) cb[n] = *(const bf16x8*)(sm + boff[n]);
#pragma unroll
    for (int m = 0; m < 4; ++m) ca0[m] = *(const bf16x8*)(sm + aoff + m * 1024);
#pragma unroll
    for (int m = 0; m < 4; ++m) ca1[m] = *(const bf16x8*)(sm + aoff + 8192 + m * 1024);

#pragma unroll 1
    for (int t = 0; t < 128; ++t) {
        int bo1 = ((t + 1) & 3) * 16384;
        bf16x8 nb[4], na0[4], na1[4];
        // reads for tile t+1 (B', A0') — drain under this tile's MFMA cluster
        if (t < 127) {
#pragma unroll
            for (int n = 0; n < 4; ++n) nb[n] = *(const bf16x8*)(sm + bo1 + boff[n]);
#pragma unroll
            for (int m = 0; m < 4; ++m) na0[m] = *(const bf16x8*)(sm + bo1 + aoff + m * 1024);
        }
        if (t < 125) { stageA(t + 3); stageB(t + 3); }
        // all tile-t fragments (read last iter) complete; the 8 new may fly
        if (t < 127) { asm volatile("s_waitcnt lgkmcnt(8)" ::: "memory"); }
        else         { asm volatile("s_waitcnt lgkmcnt(0)" ::: "memory"); }
        __builtin_amdgcn_sched_barrier(0);
        __builtin_amdgcn_s_setprio(1);
#pragma unroll
        for (int m = 0; m < 4; ++m)
#pragma unroll
            for (int n = 0; n < 4; ++n)
                acc[m][n] = __builtin_amdgcn_mfma_f32_16x16x32_bf16(ca0[m], cb[n], acc[m][n], 0, 0, 0);
        // A1' reads for tile t+1, issued mid-cluster (drain under MFMA-2)
        if (t < 127) {
#pragma unroll
            for (int m = 0; m < 4; ++m) na1[m] = *(const bf16x8*)(sm + bo1 + aoff + 8192 + m * 1024);
        }
#pragma unroll
        for (int m = 0; m < 4; ++m)
#pragma unroll
            for (int n = 0; n < 4; ++n)
                acc[4 + m][n] = __builtin_amdgcn_mfma_f32_16x16x32_bf16(ca1[m], cb[n], acc[4 + m][n], 0, 0, 0);
        __builtin_amdgcn_s_setprio(0);
        // counted vmcnt: tile t+2 resident (needed for iter t+1's reads)
        if (t < 125)       { asm volatile("s_waitcnt vmcnt(4)" ::: "memory"); }
        else if (t == 125) { asm volatile("s_waitcnt vmcnt(0)" ::: "memory"); }
        __builtin_amdgcn_s_barrier();
        if (t < 127) {
#pragma unroll
            for (int n = 0; n < 4; ++n) cb[n] = nb[n];
#pragma unroll
            for (int m = 0; m < 4; ++m) { ca0[m] = na0[m]; ca1[m] = na1[m]; }
        }
    }

    // ---- epilogue: transposed Wht store + fused s1/s2 (2 eh per block) ----
    float* red = (float*)smem;                      // 1024 floats, LDS reuse
    red[tid] = 0.f;
    red[tid + 512] = 0.f;
    float w1v[4], w2v[4];
#pragma unroll
    for (int n = 0; n < 4; ++n) {
        int eh = tn * 2 + (n >> 1);
        int o = wc * 32 + (n & 1) * 16 + llo;
        w1v[n] = a1w[eh * 128 + o];
        w2v[n] = a2w[eh * 128 + o];
    }
    __syncthreads();
#pragma unroll
    for (int mi = 0; mi < 8; ++mi) {
        int R = (mi >> 2) * 128 + wr * 64 + (mi & 3) * 16 + lhi * 4;
#pragma unroll
        for (int n = 0; n < 4; ++n) {
            int eh = tn * 2 + (n >> 1);
            int o = wc * 32 + (n & 1) * 16 + llo;
            ushort4 pk;
            pk.x = f2bf(acc[mi][n][0]);
            pk.y = f2bf(acc[mi][n][1]);
            pk.z = f2bf(acc[mi][n][2]);
            pk.w = f2bf(acc[mi][n][3]);
            *(ushort4*)(Wht + ((((size_t)eh * 16 + tm) * 128 + o) * 256 + R)) = pk;
        }
#pragma unroll
        for (int r = 0; r < 4; ++r) {
            float p10 = acc[mi][0][r] * w1v[0] + acc[mi][1][r] * w1v[1];
            float p11 = acc[mi][2][r] * w1v[2] + acc[mi][3][r] * w1v[3];
            float p20 = acc[mi][0][r] * w2v[0] + acc[mi][1][r] * w2v[1];
            float p21 = acc[mi][2][r] * w2v[2] + acc[mi][3][r] * w2v[3];
#pragma unroll
            for (int off = 1; off < 16; off <<= 1) {
                p10 += __shfl_xor(p10, off);
                p11 += __shfl_xor(p11, off);
                p20 += __shfl_xor(p20, off);
                p21 += __shfl_xor(p21, off);
            }
            if (llo == 0) {
                int row = R + r;
                atomicAdd(&red[row], p10);
                atomicAdd(&red[256 + row], p11);
                atomicAdd(&red[512 + row], p20);
                atomicAdd(&red[768 + row], p21);
            }
        }
    }
    __syncthreads();
    {
        int ehl = tid >> 8, row = tid & 255;
        int eh = tn * 2 + ehl;
        s1[eh * 4096 + tm * 256 + row] = red[ehl * 256 + row] + a1b[eh];
        s2[eh * 4096 + tm * 256 + row] = red[512 + ehl * 256 + row] + a2b[eh];
    }
}

// ---------------------------------------------------------------------------
// K6: column softmax stats, SINGLE PASS with analytic bound (shift-invariant:
// any bound >= max works; bound = leaky(s1max+s2)+8 covers |L|max for randn).
// Writes packed stat[m] = {s2, bound, cinv, 0}.
__global__ __launch_bounds__(256) void colsoft_kernel(const float* __restrict__ s1,
                                                      const float* __restrict__ s2,
                                                      const float* __restrict__ Le,
                                                      float4* __restrict__ stat) {
    int mt = blockIdx.x, b = blockIdx.y, e = blockIdx.z;
    int t = threadIdx.x;
    __shared__ float Lt[256 * 32];
    __shared__ float s1L[8 * 256];
#pragma unroll
    for (int i = 0; i < 8; ++i) s1L[i * 256 + t] = s1[(e * 8 + i) * 4096 + b * 256 + t];
    const float* Lb = Le + ((size_t)(e * 16 + b) * 256) * 256 + mt * 32;
#pragma unroll
    for (int j = 0; j < 8; ++j) {
        int f = t + 256 * j;
        int n = f >> 3, c4 = (f & 7) * 4;
        *(float4*)(Lt + n * 32 + c4) = *(const float4*)(Lb + (size_t)n * 256 + c4);
    }
    __syncthreads();
    int h = t >> 5, mm = t & 31;
    int m = mt * 32 + mm;
    float s2v = s2[(e * 8 + h) * 4096 + b * 256 + m];
    const float* s1p = s1L + h * 256;
    // s1max over 256: 8 per thread + shuffle over the 32-lane half-wave
    float s1max = -1e30f;
#pragma unroll
    for (int u = 0; u < 8; ++u) s1max = fmaxf(s1max, s1p[mm * 8 + u]);
#pragma unroll
    for (int off = 16; off; off >>= 1) s1max = fmaxf(s1max, __shfl_xor(s1max, off));
    float sm = s1max + s2v;
    float bound = (sm > 0.f ? sm : 0.2f * sm) + 8.0f;
    float sum = 0.f;
    for (int n = 0; n < 256; ++n) {
        float x = s1p[n] + s2v;
        x = x > 0.f ? x : 0.2f * x;
        x += Lt[n * 32 + mm];
        sum += __expf(x - bound);
    }
    float4 st = {s2v, bound, 1.0f / sum, 0.f};
    stat[(e * 8 + h) * 4096 + b * 256 + m] = st;
}

// ---------------------------------------------------------------------------
// K7: MFMA att-apply. Per (nt,b,eh): D[o][n] = sum_m Wht[o][m]*att[n][m]
// L loads software-pipelined: iter k+1's 4 float4s issue before iter k's MFMA.
// LAST=0: st1b bf16 elu; LAST=1: h2 bf16 (no elu)
template <int LAST>
__global__ __launch_bounds__(256) void att_mfma_kernel(const float* __restrict__ s1,
                                                       const float4* __restrict__ stat,
                                                       const float* __restrict__ Le,
                                                       const bf16* __restrict__ Wht,
                                                       const float* __restrict__ sb,
                                                       bf16* __restrict__ outb) {
    int nt = blockIdx.x;   // 0..1
    int b = blockIdx.y;    // 0..15
    int eh = blockIdx.z;   // 0..31
    int e = eh >> 3;
    int tid = threadIdx.x;
    int w = tid >> 6, l = tid & 63;
    int q = l >> 4, mn = l & 15;
    __shared__ __align__(16) bf16 As[128 * 32];
    __shared__ __align__(16) bf16 Bs[128 * 40];   // att rows padded 32->40
    __shared__ float s1L[128];
    __shared__ __align__(16) float4 stL[256];

    int base = eh * 4096 + b * 256;
    if (tid < 128) s1L[tid] = s1[base + nt * 128 + tid];
    stL[tid] = stat[base + tid];
    __syncthreads();

    const bf16* Whtp = Wht + ((size_t)eh * 16 + b) * 32768;
    int nl = tid >> 1, mh = (tid & 1) * 16;
    const float* Lrow = Le + (((size_t)(e * 16 + b) * 256) + nt * 128 + nl) * 256;
    float s1v = s1L[nl];
    int srow = l >> 2;
    int sq = (l & 3) ^ ((l >> 3) & 3);
    int scol = sq * 8;
    int rsw = ((mn >> 1) & 3) << 3;

    f32x4 acc[4][4];
#pragma unroll
    for (int i = 0; i < 4; i++)
#pragma unroll
        for (int j = 0; j < 4; j++) acc[i][j] = (f32x4){0.f, 0.f, 0.f, 0.f};

    int wr = (w >> 1) * 64, wc = (w & 1) * 64;

    // prefetch L for iteration 0
    float4 lv[4];
#pragma unroll
    for (int jj = 0; jj < 4; ++jj) lv[jj] = *(const float4*)(Lrow + mh + jj * 4);

    for (int k0 = 0; k0 < 256; k0 += 32) {
#pragma unroll
        for (int u = 0; u < 2; ++u) {
            int i = 2 * w + u;
            gll16(Whtp + (size_t)(i * 16 + srow) * 256 + k0 + scol, (char*)As + i * 1024);
        }
        float4 cur[4];
#pragma unroll
        for (int jj = 0; jj < 4; ++jj) cur[jj] = lv[jj];
        if (k0 + 32 < 256) {
#pragma unroll
            for (int jj = 0; jj < 4; ++jj)
                lv[jj] = *(const float4*)(Lrow + k0 + 32 + mh + jj * 4);
        }
#pragma unroll
        for (int jj = 0; jj < 4; ++jj) {
            int mb = mh + jj * 4;
            float av[4];
#pragma unroll
            for (int c = 0; c < 4; ++c) {
                int m = k0 + mb + c;
                float4 stv = stL[m];
                float x = s1v + stv.x;
                x = x > 0.f ? x : 0.2f * x;
                x += ((const float*)&cur[jj])[c];
                av[c] = __expf(x - stv.y) * stv.z;
            }
            unsigned int u01 = (unsigned int)f2bf(av[0]) | ((unsigned int)f2bf(av[1]) << 16);
            unsigned int u23 = (unsigned int)f2bf(av[2]) | ((unsigned int)f2bf(av[3]) << 16);
            unsigned int* bp = (unsigned int*)Bs + (nl * 40 + mb) / 2;
            bp[0] = u01;
            bp[1] = u23;
        }
        __syncthreads();
        bf16x8 af[4], bfr[4];
#pragma unroll
        for (int i = 0; i < 4; ++i) {
            af[i]  = *(const bf16x8*)(As + (wr + i * 16 + mn) * 32 + ((q << 3) ^ rsw));
            bfr[i] = *(const bf16x8*)(Bs + (wc + i * 16 + mn) * 40 + q * 8);
        }
#pragma unroll
        for (int i = 0; i < 4; ++i)
#pragma unroll
            for (int j = 0; j < 4; ++j)
                acc[i][j] = __builtin_amdgcn_mfma_f32_16x16x32_bf16(af[i], bfr[j], acc[i][j], 0, 0, 0);
        __syncthreads();
    }
#pragma unroll
    for (int i = 0; i < 4; ++i) {
        int o0 = wr + i * 16 + q * 4;
        float4 sbv = *(const float4*)(sb + eh * 128 + o0);
#pragma unroll
        for (int j = 0; j < 4; ++j) {
            int n = wc + j * 16 + mn;
            float v0 = acc[i][j][0] + sbv.x;
            float v1 = acc[i][j][1] + sbv.y;
            float v2 = acc[i][j][2] + sbv.z;
            float v3 = acc[i][j][3] + sbv.w;
            if (LAST == 0) {
                v0 = v0 > 0.f ? v0 : __expf(v0) - 1.f;
                v1 = v1 > 0.f ? v1 : __expf(v1) - 1.f;
                v2 = v2 > 0.f ? v2 : __expf(v2) - 1.f;
                v3 = v3 > 0.f ? v3 : __expf(v3) - 1.f;
                ushort4 pk = {f2bf(v0), f2bf(v1), f2bf(v2), f2bf(v3)};
                *(ushort4*)(outb + (size_t)(b * 256 + nt * 128 + n) * 4096 + eh * Dq + o0) = pk;
            } else {
                ushort4 pk = {f2bf(v0), f2bf(v1), f2bf(v2), f2bf(v3)};
                *(ushort4*)(outb + ((size_t)eh * 4096 + b * 256 + nt * 128 + n) * Dq + o0) = pk;
            }
        }
    }
}

// ---------------------------------------------------------------------------
// K8: fused: st2[bn,o] = (1/32)*sum_eh h2b[eh,bn,o]; aw[bn] = sigmoid(st2.attW+attb)
__global__ __launch_bounds__(256) void reduce_aw_kernel(const bf16* __restrict__ h2b,
                                                        const float* __restrict__ attW,
                                                        const float* __restrict__ attb,
                                                        float* __restrict__ st2,
                                                        float* __restrict__ aw) {
    int t = threadIdx.x;
    int rl = t >> 7, o = t & 127;
    int r = blockIdx.x * 2 + rl;
    float acc = 0.f;
#pragma unroll
    for (int eh = 0; eh < EH; ++eh)
        acc += __bfloat162float(h2b[((size_t)eh * 4096 + r) * 128 + o]);
    acc *= (1.0f / 32.0f);
    st2[(size_t)r * 128 + o] = acc;
    float p = acc * attW[o];
#pragma unroll
    for (int off = 32; off; off >>= 1) p += __shfl_down(p, off);
    __shared__ float part[4];
    if ((t & 63) == 0) part[t >> 6] = p;
    __syncthreads();
    if (t == 0) aw[r] = 1.0f / (1.0f + __expf(-(part[0] + part[1] + attb[0])));
    if (t == 128) aw[r] = 1.0f / (1.0f + __expf(-(part[2] + part[3] + attb[0])));
}

// ---------------------------------------------------------------------------
// K10: out[b,d] = (1/256) * ( sum_o z[b,o]*outW[o,d] + sumaw[b]*outb[d] )
__global__ __launch_bounds__(128) void final_kernel(const float* __restrict__ st2,
                                                    const float* __restrict__ aw,
                                                    const float* __restrict__ outW,
                                                    const float* __restrict__ outb,
                                                    float* __restrict__ out) {
    int b = blockIdx.x;
    int t = threadIdx.x;
    __shared__ float awL[256], zL[128];
    awL[t] = aw[b * 256 + t];
    awL[t + 128] = aw[b * 256 + t + 128];
    __syncthreads();
    float z = 0.f;
    for (int n = 0; n < 256; ++n) z += awL[n] * st2[(size_t)(b * 256 + n) * Dq + t];
    float sa = 0.f;
    for (int n = 0; n < 256; ++n) sa += awL[n];
    zL[t] = z;
    __syncthreads();
    float acc = sa * outb[t];
    for (int o = 0; o < Dq; ++o) acc += zL[o] * outW[o * Dq + t];
    out[b * Dq + t] = acc * (1.0f / 256.0f);
}

// ---------------------------------------------------------------------------
extern "C" void kernel_launch(void* const* d_in, const int* in_sizes, int n_in,
                              void* d_out, int out_size, void* d_ws, size_t ws_size,
                              hipStream_t stream) {
    const int* nf = (const int*)d_in[0];
    const float* L = (const float*)d_in[1];
    const float* emb = (const float*)d_in[2];
    const float* W0 = (const float*)d_in[3];
    const float* W1 = (const float*)d_in[4];
    const float* a1w0 = (const float*)d_in[5];
    const float* a1b0 = (const float*)d_in[6];
    const float* a2w0 = (const float*)d_in[7];
    const float* a2b0 = (const float*)d_in[8];
    const float* a1w1 = (const float*)d_in[9];
    const float* a1b1 = (const float*)d_in[10];
    const float* a2w1 = (const float*)d_in[11];
    const float* a2b1 = (const float*)d_in[12];
    const float* sb0 = (const float*)d_in[13];
    const float* sb1 = (const float*)d_in[14];
    const float* outW = (const float*)d_in[15];
    const float* outb = (const float*)d_in[16];
    const float* attW = (const float*)d_in[17];
    const float* attb = (const float*)d_in[18];

    char* p = (char*)d_ws;
    bf16* st0b = (bf16*)(p);                        // [0, 1M)
    bf16* W0T  = (bf16*)(p + 1048576);              // [1M, 2M)
    bf16* W1T  = (bf16*)(p + 2097152);              // [2M, 34M)   dead after gemm1
    bf16* st1b = (bf16*)(p + 35651584);             // [34M, 66M)  dead after gemm1
    bf16* h2b  = (bf16*)(p + 2097152);              // [2M, 34M)   written by att1
    float* Le  = (float*)(p + 69206016);            // [66M, 82M)
    bf16* Wht  = (bf16*)(p + 85983232);             // [82M, 114M)
    float* s1  = (float*)(p + 119537664);           // 512K
    float* s2  = (float*)(p + 120061952);           // 512K
    float4* stat = (float4*)(p + 120586240);        // 2M
    float* st2 = (float*)(p);                       // reuse st0b/W0T (2 MB)
    float* aw  = s1;                                // reuse
    float* outp = (float*)d_out;

    prep_kernel<<<10368, 256, 0, stream>>>(nf, emb, W0, W1, L, st0b, W0T, W1T, Le);

    mfma_gemm_kernel<<<1024, 256, 0, stream>>>(st0b, W0T, Wht, a1w0, a1b0, a2w0, a2b0, s1, s2, 128);
    colsoft_kernel<<<dim3(8, 16, 4), 256, 0, stream>>>(s1, s2, Le, stat);
    att_mfma_kernel<0><<<dim3(2, 16, 32), 256, 0, stream>>>(s1, stat, Le, Wht, sb0, st1b);

    gemm4k_kernel<<<256, 512, 0, stream>>>(st1b, W1T, Wht, a1w1, a1b1, a2w1, a2b1, s1, s2);
    colsoft_kernel<<<dim3(8, 16, 4), 256, 0, stream>>>(s1, s2, Le, stat);
    att_mfma_kernel<1><<<dim3(2, 16, 32), 256, 0, stream>>>(s1, stat, Le, Wht, sb1, h2b);

    reduce_aw_kernel<<<2048, 256, 0, stream>>>(h2b, attW, attb, st2, aw);
    final_kernel<<<16, 128, 0, stream>>>(st2, aw, outW, outb, outp);
}

// Round 4
// 429.519 us; speedup vs baseline: 1.0271x; 1.0271x over previous
//
#include <hip/hip_runtime.h>
#include <hip/hip_bf16.h>

// Problem constants
#define Bq 16
#define Nq 256
#define E1q 4
#define Hq 8
#define Dq 128
#define EH 32
#define BN 4096

typedef __hip_bfloat16 bf16;
typedef short bf16x8 __attribute__((ext_vector_type(8)));
typedef float f32x4 __attribute__((ext_vector_type(4)));

__device__ __forceinline__ void gll16(const void* gptr, void* lptr) {
    __builtin_amdgcn_global_load_lds(
        (const __attribute__((address_space(1))) void*)gptr,
        (__attribute__((address_space(3))) void*)lptr, 16, 0, 0);
}

__device__ __forceinline__ unsigned short f2bf(float v) {
    __hip_bfloat16 h = __float2bfloat16(v);
    return *(unsigned short*)&h;
}

// ---------------------------------------------------------------------------
// K0: fused prep: gather st0b | transpose W0 | transpose W1 | pack Le
__device__ __forceinline__ void transpose_tile(const float* __restrict__ W,
                                               bf16* __restrict__ WT, int K,
                                               int kt, int nt, int eh,
                                               float (*tile)[65], int tid) {
    int tr = tid >> 6, tc = tid & 63;
    const float* src = W + ((size_t)eh * K + kt * 64) * 128 + nt * 64;
#pragma unroll
    for (int p = 0; p < 16; ++p) {
        int r = p * 4 + tr;
        tile[r][tc] = src[(size_t)r * 128 + tc];
    }
    __syncthreads();
    bf16* dst = WT + ((size_t)eh * 128 + nt * 64) * K + kt * 64;
#pragma unroll
    for (int p = 0; p < 16; ++p) {
        int n = p * 4 + tr;
        dst[(size_t)n * K + tc] = __float2bfloat16(tile[tc][n]);
    }
}

__global__ __launch_bounds__(256) void prep_kernel(const int* __restrict__ nf,
                                                   const float* __restrict__ emb,
                                                   const float* __restrict__ W0,
                                                   const float* __restrict__ W1,
                                                   const float* __restrict__ L,
                                                   bf16* __restrict__ st0b,
                                                   bf16* __restrict__ W0T,
                                                   bf16* __restrict__ W1T,
                                                   float* __restrict__ Le) {
    int bid = blockIdx.x;
    int t = threadIdx.x;
    __shared__ float tile[64][65];
    if (bid < 2048) {
        int i = bid * 256 + t;
        int row = i >> 7, col = i & 127;
        st0b[i] = __float2bfloat16(emb[nf[row] * Dq + col]);
    } else if (bid < 2176) {
        int id2 = bid - 2048;                       // (2 kt, 2 nt, 32 eh)
        transpose_tile(W0, W0T, 128, id2 & 1, (id2 >> 1) & 1, id2 >> 2, tile, t);
    } else if (bid < 6272) {
        int id3 = bid - 2176;                       // (64 kt, 2 nt, 32 eh)
        transpose_tile(W1, W1T, 4096, id3 & 63, (id3 >> 6) & 1, id3 >> 7, tile, t);
    } else {
        int idx = (bid - 6272) * 256 + t;           // 0..1048575
        float4 v = *(const float4*)(L + (size_t)idx * 4);
        Le[idx] = v.x;
        Le[1048576 + idx] = v.y;
        Le[2097152 + idx] = v.z;
        Le[3145728 + idx] = v.w;
    }
}

// ---------------------------------------------------------------------------
// K4: bf16 MFMA GEMM — LAYER 0 ONLY (K=128), 128-tile 2-barrier structure.
__global__ __launch_bounds__(256) void mfma_gemm_kernel(const bf16* __restrict__ Ab,
                                                        const bf16* __restrict__ Bt,
                                                        bf16* __restrict__ Wht,
                                                        const float* __restrict__ a1w,
                                                        const float* __restrict__ a1b,
                                                        const float* __restrict__ a2w,
                                                        const float* __restrict__ a2b,
                                                        float* __restrict__ s1,
                                                        float* __restrict__ s2, int K) {
    int id = blockIdx.x;
    int xcd = id & 7, slot = id >> 3;
    int eh = (slot & 3) * 8 + xcd;
    int rt = slot >> 2;
    int tid = threadIdx.x;
    int w = tid >> 6, l = tid & 63;
    int q = l >> 4, mn = l & 15;
    __shared__ __align__(16) bf16 As[128 * 64];
    __shared__ __align__(16) bf16 Bs[128 * 64];
    __shared__ float red1[128], red2[128];
    const bf16* Ap = Ab + (size_t)(rt * 128) * K;
    const bf16* Bp = Bt + (size_t)eh * 128 * K;
    int lr = l >> 3;                      // local row within 8-row chunk
    int g = (l & 7) ^ lr;                 // swizzled global k-quad for staging
    int gcol = g * 8;

    if (tid < 128) { red1[tid] = 0.f; red2[tid] = 0.f; }

    f32x4 acc[4][4];
#pragma unroll
    for (int i = 0; i < 4; i++)
#pragma unroll
        for (int j = 0; j < 4; j++) acc[i][j] = (f32x4){0.f, 0.f, 0.f, 0.f};

    int wr = (w >> 1) * 64, wc = (w & 1) * 64;
    int msw = mn & 7;

    for (int k0 = 0; k0 < K; k0 += 64) {
#pragma unroll
        for (int u = 0; u < 4; ++u) {
            int i = w * 4 + u;            // chunk 0..15
            int r = i * 8 + lr;
            gll16(Ap + (size_t)r * K + k0 + gcol, (char*)As + i * 1024);
            gll16(Bp + (size_t)r * K + k0 + gcol, (char*)Bs + i * 1024);
        }
        __syncthreads();
#pragma unroll
        for (int kk = 0; kk < 2; ++kk) {
            int qb = ((kk * 4 + q) ^ msw) * 16;
            bf16x8 af[4], bfr[4];
#pragma unroll
            for (int i = 0; i < 4; ++i) {
                af[i]  = *(const bf16x8*)((const char*)As + (wr + i * 16 + mn) * 128 + qb);
                bfr[i] = *(const bf16x8*)((const char*)Bs + (wc + i * 16 + mn) * 128 + qb);
            }
#pragma unroll
            for (int i = 0; i < 4; ++i)
#pragma unroll
                for (int j = 0; j < 4; ++j)
                    acc[i][j] = __builtin_amdgcn_mfma_f32_16x16x32_bf16(af[i], bfr[j], acc[i][j], 0, 0, 0);
        }
        __syncthreads();
    }
    // transposed bf16 store
#pragma unroll
    for (int i = 0; i < 4; ++i) {
        int r0 = rt * 128 + wr + i * 16 + q * 4;
        int b = r0 >> 8, m = r0 & 255;
#pragma unroll
        for (int j = 0; j < 4; ++j) {
            int o = wc + j * 16 + mn;
            ushort4 pk;
            pk.x = f2bf(acc[i][j][0]);
            pk.y = f2bf(acc[i][j][1]);
            pk.z = f2bf(acc[i][j][2]);
            pk.w = f2bf(acc[i][j][3]);
            *(ushort4*)(Wht + ((((size_t)eh * 16 + b) * 128 + o) * 256 + m)) = pk;
        }
    }
    // fused s1/s2
    float w1v[4], w2v[4];
#pragma unroll
    for (int j = 0; j < 4; ++j) {
        int o = wc + j * 16 + mn;
        w1v[j] = a1w[eh * 128 + o];
        w2v[j] = a2w[eh * 128 + o];
    }
#pragma unroll
    for (int i = 0; i < 4; ++i)
#pragma unroll
        for (int r = 0; r < 4; ++r) {
            float p1 = 0.f, p2 = 0.f;
#pragma unroll
            for (int j = 0; j < 4; ++j) {
                p1 += acc[i][j][r] * w1v[j];
                p2 += acc[i][j][r] * w2v[j];
            }
#pragma unroll
            for (int off = 1; off < 16; off <<= 1) {
                p1 += __shfl_xor(p1, off);
                p2 += __shfl_xor(p2, off);
            }
            if (mn == 0) {
                int row = wr + i * 16 + q * 4 + r;
                atomicAdd(&red1[row], p1);
                atomicAdd(&red2[row], p2);
            }
        }
    __syncthreads();
    if (tid < 128) {
        int rg = rt * 128 + tid;
        s1[eh * 4096 + rg] = red1[tid] + a1b[eh];
        s2[eh * 4096 + rg] = red2[tid] + a2b[eh];
    }
}

// ---------------------------------------------------------------------------
// K4b: LAYER-1 GEMM (4096^3 bf16), 256x256 tile, register software pipeline,
// 2x-unrolled ping-pong (R3 post-mortem: the unroll-1 rotation cost 48
// v_movs/wave/tile -> VALUBusy 27%; ping-pong sets X/Y eliminate them).
// Body A: MFMA tile t from X, read tile t+1 into Y, stage t+3.
// Body B: MFMA tile t+1 from Y, read tile t+2 into X, stage t+4.
// Per body: lgkm(12) = previous body's 12 reads done (12 new may fly, they
// drain UNDER this body's 32-MFMA cluster); vmcnt(4) = tile t+3 resident
// for the body that reads it (ledger simulated from prologue); 1 barrier.
// Buffer safety: stage(t+3) overwrites tile t-1's buf; its reads completed
// before a barrier two bodies back. Tail: reads guarded t+2<128, stages
// t+3/t+4<128, vmcnt(0) from t>=124, lgkm(0) in the last body.
__global__ __launch_bounds__(512, 2) void gemm4k_kernel(const bf16* __restrict__ Ab,
                                                        const bf16* __restrict__ Bt,
                                                        bf16* __restrict__ Wht,
                                                        const float* __restrict__ a1w,
                                                        const float* __restrict__ a1b,
                                                        const float* __restrict__ a2w,
                                                        const float* __restrict__ a2b,
                                                        float* __restrict__ s1,
                                                        float* __restrict__ s2) {
    __shared__ __align__(16) char smem[131072];     // [0,64K): A ring, [64K,128K): B ring
    int bid = blockIdx.x;
    int wg = (bid & 7) * 32 + (bid >> 3);           // XCD-bijective (256 % 8 == 0)
    int tm = wg >> 4, tn = wg & 15;                 // tm: batch/row tile, tn: eh-pair
    int tid = threadIdx.x;
    int wid = tid >> 6, l = tid & 63;
    int wr = wid >> 2, wc = wid & 3;                // wave 2M x 4N
    int lhi = l >> 4, llo = l & 15;
    int sa = (lhi ^ ((l >> 1) & 3)) << 4;           // read-side swizzled 16B slot
    int skq = (l & 3) ^ ((l >> 3) & 3);             // stage-side pre-swizzled k-quad

    const bf16* Ap = Ab + (size_t)tm * 256 * 4096;
    const bf16* Bp = Bt + (size_t)tn * 256 * 4096;
    const bf16* sA = Ap + (size_t)(wid * 16 + (l >> 2)) * 4096 + skq * 8;
    const bf16* sB = Bp + (size_t)(wid * 16 + (l >> 2)) * 4096 + skq * 8;
    char* dA = (char*)smem + wid * 1024;            // wave-uniform LDS dests
    char* dB = (char*)smem + 65536 + wid * 1024;

    auto stageA = [&](int tt) {
        int bo = (tt & 3) * 16384;
        gll16(sA + tt * 32, dA + bo);
        gll16(sA + (size_t)128 * 4096 + tt * 32, dA + bo + 8192);
    };
    auto stageB = [&](int tt) {
        int bo = (tt & 3) * 16384;
        gll16(sB + tt * 32, dB + bo);
        gll16(sB + (size_t)128 * 4096 + tt * 32, dB + bo + 8192);
    };

    f32x4 acc[8][4];
#pragma unroll
    for (int i = 0; i < 8; ++i)
#pragma unroll
        for (int j = 0; j < 4; ++j) acc[i][j] = (f32x4){0.f, 0.f, 0.f, 0.f};

    // read byte offsets (A rows: mh*128 + wr*64 + m*16 + llo; B cols likewise)
    int aoff = ((wr * 64 + llo) << 6) + sa;         // + buf*16384 + mh*8192 + m*1024
    int boff[4];
#pragma unroll
    for (int n = 0; n < 4; ++n)
        boff[n] = 65536 + (((n >> 1) * 128 + wc * 32 + (n & 1) * 16 + llo) << 6) + sa;

    // prologue: tiles 0,1,2 staged; tiles 0,1 resident; read tile-0 frags (X)
    stageA(0); stageB(0); stageA(1); stageB(1); stageA(2); stageB(2);
    asm volatile("s_waitcnt vmcnt(4)" ::: "memory");
    __builtin_amdgcn_s_barrier();
    const char* sm = (const char*)smem;
    bf16x8 xb[4], xa0[4], xa1[4], yb[4], ya0[4], ya1[4];
#pragma unroll
    for (int n = 0; n < 4; ++n) xb[n] = *(const bf16x8*)(sm + boff[n]);
#pragma unroll
    for (int m = 0; m < 4; ++m) xa0[m] = *(const bf16x8*)(sm + aoff + m * 1024);
#pragma unroll
    for (int m = 0; m < 4; ++m) xa1[m] = *(const bf16x8*)(sm + aoff + 8192 + m * 1024);

#pragma unroll 1
    for (int t = 0; t < 128; t += 2) {
        // ---- body A: MFMA tile t (X); read tile t+1 (Y); stage t+3 ----
        {
            int bo1 = ((t + 1) & 3) * 16384;
#pragma unroll
            for (int n = 0; n < 4; ++n) yb[n] = *(const bf16x8*)(sm + bo1 + boff[n]);
#pragma unroll
            for (int m = 0; m < 4; ++m) ya0[m] = *(const bf16x8*)(sm + bo1 + aoff + m * 1024);
#pragma unroll
            for (int m = 0; m < 4; ++m) ya1[m] = *(const bf16x8*)(sm + bo1 + aoff + 8192 + m * 1024);
            if (t + 3 < 128) { stageA(t + 3); stageB(t + 3); }
            asm volatile("s_waitcnt lgkmcnt(12)" ::: "memory");
            __builtin_amdgcn_sched_barrier(0);
            __builtin_amdgcn_s_setprio(1);
#pragma unroll
            for (int m = 0; m < 4; ++m)
#pragma unroll
                for (int n = 0; n < 4; ++n)
                    acc[m][n] = __builtin_amdgcn_mfma_f32_16x16x32_bf16(xa0[m], xb[n], acc[m][n], 0, 0, 0);
#pragma unroll
            for (int m = 0; m < 4; ++m)
#pragma unroll
                for (int n = 0; n < 4; ++n)
                    acc[4 + m][n] = __builtin_amdgcn_mfma_f32_16x16x32_bf16(xa1[m], xb[n], acc[4 + m][n], 0, 0, 0);
            __builtin_amdgcn_s_setprio(0);
            if (t < 124) { asm volatile("s_waitcnt vmcnt(4)" ::: "memory"); }
            else         { asm volatile("s_waitcnt vmcnt(0)" ::: "memory"); }
            __builtin_amdgcn_s_barrier();
        }
        // ---- body B: MFMA tile t+1 (Y); read tile t+2 (X); stage t+4 ----
        {
            if (t + 2 < 128) {
                int bo2 = ((t + 2) & 3) * 16384;
#pragma unroll
                for (int n = 0; n < 4; ++n) xb[n] = *(const bf16x8*)(sm + bo2 + boff[n]);
#pragma unroll
                for (int m = 0; m < 4; ++m) xa0[m] = *(const bf16x8*)(sm + bo2 + aoff + m * 1024);
#pragma unroll
                for (int m = 0; m < 4; ++m) xa1[m] = *(const bf16x8*)(sm + bo2 + aoff + 8192 + m * 1024);
            }
            if (t + 4 < 128) { stageA(t + 4); stageB(t + 4); }
            if (t + 2 < 128) { asm volatile("s_waitcnt lgkmcnt(12)" ::: "memory"); }
            else             { asm volatile("s_waitcnt lgkmcnt(0)" ::: "memory"); }
            __builtin_amdgcn_sched_barrier(0);
            __builtin_amdgcn_s_setprio(1);
#pragma unroll
            for (int m = 0; m < 4; ++m)
#pragma unroll
                for (int n = 0; n < 4; ++n)
                    acc[m][n] = __builtin_amdgcn_mfma_f32_16x16x32_bf16(ya0[m], yb[n], acc[m][n], 0, 0, 0);
#pragma unroll
            for (int m = 0; m < 4; ++m)
#pragma unroll
                for (int n = 0; n < 4; ++n)
                    acc[4 + m][n] = __builtin_amdgcn_mfma_f32_16x16x32_bf16(ya1[m], yb[n], acc[4 + m][n], 0, 0, 0);
            __builtin_amdgcn_s_setprio(0);
            if (t < 124) { asm volatile("s_waitcnt vmcnt(4)" ::: "memory"); }
            else         { asm volatile("s_waitcnt vmcnt(0)" ::: "memory"); }
            __builtin_amdgcn_s_barrier();
        }
    }

    // ---- epilogue: transposed Wht store + fused s1/s2 (2 eh per block) ----
    float* red = (float*)smem;                      // 1024 floats, LDS reuse
    red[tid] = 0.f;
    red[tid + 512] = 0.f;
    float w1v[4], w2v[4];
#pragma unroll
    for (int n = 0; n < 4; ++n) {
        int eh = tn * 2 + (n >> 1);
        int o = wc * 32 + (n & 1) * 16 + llo;
        w1v[n] = a1w[eh * 128 + o];
        w2v[n] = a2w[eh * 128 + o];
    }
    __syncthreads();
#pragma unroll
    for (int mi = 0; mi < 8; ++mi) {
        int R = (mi >> 2) * 128 + wr * 64 + (mi & 3) * 16 + lhi * 4;
#pragma unroll
        for (int n = 0; n < 4; ++n) {
            int eh = tn * 2 + (n >> 1);
            int o = wc * 32 + (n & 1) * 16 + llo;
            ushort4 pk;
            pk.x = f2bf(acc[mi][n][0]);
            pk.y = f2bf(acc[mi][n][1]);
            pk.z = f2bf(acc[mi][n][2]);
            pk.w = f2bf(acc[mi][n][3]);
            *(ushort4*)(Wht + ((((size_t)eh * 16 + tm) * 128 + o) * 256 + R)) = pk;
        }
#pragma unroll
        for (int r = 0; r < 4; ++r) {
            float p10 = acc[mi][0][r] * w1v[0] + acc[mi][1][r] * w1v[1];
            float p11 = acc[mi][2][r] * w1v[2] + acc[mi][3][r] * w1v[3];
            float p20 = acc[mi][0][r] * w2v[0] + acc[mi][1][r] * w2v[1];
            float p21 = acc[mi][2][r] * w2v[2] + acc[mi][3][r] * w2v[3];
#pragma unroll
            for (int off = 1; off < 16; off <<= 1) {
                p10 += __shfl_xor(p10, off);
                p11 += __shfl_xor(p11, off);
                p20 += __shfl_xor(p20, off);
                p21 += __shfl_xor(p21, off);
            }
            if (llo == 0) {
                int row = R + r;
                atomicAdd(&red[row], p10);
                atomicAdd(&red[256 + row], p11);
                atomicAdd(&red[512 + row], p20);
                atomicAdd(&red[768 + row], p21);
            }
        }
    }
    __syncthreads();
    {
        int ehl = tid >> 8, row = tid & 255;
        int eh = tn * 2 + ehl;
        s1[eh * 4096 + tm * 256 + row] = red[ehl * 256 + row] + a1b[eh];
        s2[eh * 4096 + tm * 256 + row] = red[512 + ehl * 256 + row] + a2b[eh];
    }
}

// ---------------------------------------------------------------------------
// K6: column softmax stats, SINGLE PASS with analytic bound (shift-invariant:
// any bound >= max works; bound = leaky(s1max+s2)+8 covers |L|max for randn).
// Writes packed stat[m] = {s2, bound, cinv, 0}.
__global__ __launch_bounds__(256) void colsoft_kernel(const float* __restrict__ s1,
                                                      const float* __restrict__ s2,
                                                      const float* __restrict__ Le,
                                                      float4* __restrict__ stat) {
    int mt = blockIdx.x, b = blockIdx.y, e = blockIdx.z;
    int t = threadIdx.x;
    __shared__ float Lt[256 * 32];
    __shared__ float s1L[8 * 256];
#pragma unroll
    for (int i = 0; i < 8; ++i) s1L[i * 256 + t] = s1[(e * 8 + i) * 4096 + b * 256 + t];
    const float* Lb = Le + ((size_t)(e * 16 + b) * 256) * 256 + mt * 32;
#pragma unroll
    for (int j = 0; j < 8; ++j) {
        int f = t + 256 * j;
        int n = f >> 3, c4 = (f & 7) * 4;
        *(float4*)(Lt + n * 32 + c4) = *(const float4*)(Lb + (size_t)n * 256 + c4);
    }
    __syncthreads();
    int h = t >> 5, mm = t & 31;
    int m = mt * 32 + mm;
    float s2v = s2[(e * 8 + h) * 4096 + b * 256 + m];
    const float* s1p = s1L + h * 256;
    // s1max over 256: 8 per thread + shuffle over the 32-lane half-wave
    float s1max = -1e30f;
#pragma unroll
    for (int u = 0; u < 8; ++u) s1max = fmaxf(s1max, s1p[mm * 8 + u]);
#pragma unroll
    for (int off = 16; off; off >>= 1) s1max = fmaxf(s1max, __shfl_xor(s1max, off));
    float sm = s1max + s2v;
    float bound = (sm > 0.f ? sm : 0.2f * sm) + 8.0f;
    float sum = 0.f;
    for (int n = 0; n < 256; ++n) {
        float x = s1p[n] + s2v;
        x = x > 0.f ? x : 0.2f * x;
        x += Lt[n * 32 + mm];
        sum += __expf(x - bound);
    }
    float4 st = {s2v, bound, 1.0f / sum, 0.f};
    stat[(e * 8 + h) * 4096 + b * 256 + m] = st;
}

// ---------------------------------------------------------------------------
// K7: MFMA att-apply. Per (nt,b,eh): D[o][n] = sum_m Wht[o][m]*att[n][m]
// L loads software-pipelined: iter k+1's 4 float4s issue before iter k's MFMA.
// LAST=0: st1b bf16 elu; LAST=1: h2 bf16 (no elu)
template <int LAST>
__global__ __launch_bounds__(256) void att_mfma_kernel(const float* __restrict__ s1,
                                                       const float4* __restrict__ stat,
                                                       const float* __restrict__ Le,
                                                       const bf16* __restrict__ Wht,
                                                       const float* __restrict__ sb,
                                                       bf16* __restrict__ outb) {
    int nt = blockIdx.x;   // 0..1
    int b = blockIdx.y;    // 0..15
    int eh = blockIdx.z;   // 0..31
    int e = eh >> 3;
    int tid = threadIdx.x;
    int w = tid >> 6, l = tid & 63;
    int q = l >> 4, mn = l & 15;
    __shared__ __align__(16) bf16 As[128 * 32];
    __shared__ __align__(16) bf16 Bs[128 * 40];   // att rows padded 32->40
    __shared__ float s1L[128];
    __shared__ __align__(16) float4 stL[256];

    int base = eh * 4096 + b * 256;
    if (tid < 128) s1L[tid] = s1[base + nt * 128 + tid];
    stL[tid] = stat[base + tid];
    __syncthreads();

    const bf16* Whtp = Wht + ((size_t)eh * 16 + b) * 32768;
    int nl = tid >> 1, mh = (tid & 1) * 16;
    const float* Lrow = Le + (((size_t)(e * 16 + b) * 256) + nt * 128 + nl) * 256;
    float s1v = s1L[nl];
    int srow = l >> 2;
    int sq = (l & 3) ^ ((l >> 3) & 3);
    int scol = sq * 8;
    int rsw = ((mn >> 1) & 3) << 3;

    f32x4 acc[4][4];
#pragma unroll
    for (int i = 0; i < 4; i++)
#pragma unroll
        for (int j = 0; j < 4; j++) acc[i][j] = (f32x4){0.f, 0.f, 0.f, 0.f};

    int wr = (w >> 1) * 64, wc = (w & 1) * 64;

    // prefetch L for iteration 0
    float4 lv[4];
#pragma unroll
    for (int jj = 0; jj < 4; ++jj) lv[jj] = *(const float4*)(Lrow + mh + jj * 4);

    for (int k0 = 0; k0 < 256; k0 += 32) {
#pragma unroll
        for (int u = 0; u < 2; ++u) {
            int i = 2 * w + u;
            gll16(Whtp + (size_t)(i * 16 + srow) * 256 + k0 + scol, (char*)As + i * 1024);
        }
        float4 cur[4];
#pragma unroll
        for (int jj = 0; jj < 4; ++jj) cur[jj] = lv[jj];
        if (k0 + 32 < 256) {
#pragma unroll
            for (int jj = 0; jj < 4; ++jj)
                lv[jj] = *(const float4*)(Lrow + k0 + 32 + mh + jj * 4);
        }
#pragma unroll
        for (int jj = 0; jj < 4; ++jj) {
            int mb = mh + jj * 4;
            float av[4];
#pragma unroll
            for (int c = 0; c < 4; ++c) {
                int m = k0 + mb + c;
                float4 stv = stL[m];
                float x = s1v + stv.x;
                x = x > 0.f ? x : 0.2f * x;
                x += ((const float*)&cur[jj])[c];
                av[c] = __expf(x - stv.y) * stv.z;
            }
            unsigned int u01 = (unsigned int)f2bf(av[0]) | ((unsigned int)f2bf(av[1]) << 16);
            unsigned int u23 = (unsigned int)f2bf(av[2]) | ((unsigned int)f2bf(av[3]) << 16);
            unsigned int* bp = (unsigned int*)Bs + (nl * 40 + mb) / 2;
            bp[0] = u01;
            bp[1] = u23;
        }
        __syncthreads();
        bf16x8 af[4], bfr[4];
#pragma unroll
        for (int i = 0; i < 4; ++i) {
            af[i]  = *(const bf16x8*)(As + (wr + i * 16 + mn) * 32 + ((q << 3) ^ rsw));
            bfr[i] = *(const bf16x8*)(Bs + (wc + i * 16 + mn) * 40 + q * 8);
        }
#pragma unroll
        for (int i = 0; i < 4; ++i)
#pragma unroll
            for (int j = 0; j < 4; ++j)
                acc[i][j] = __builtin_amdgcn_mfma_f32_16x16x32_bf16(af[i], bfr[j], acc[i][j], 0, 0, 0);
        __syncthreads();
    }
#pragma unroll
    for (int i = 0; i < 4; ++i) {
        int o0 = wr + i * 16 + q * 4;
        float4 sbv = *(const float4*)(sb + eh * 128 + o0);
#pragma unroll
        for (int j = 0; j < 4; ++j) {
            int n = wc + j * 16 + mn;
            float v0 = acc[i][j][0] + sbv.x;
            float v1 = acc[i][j][1] + sbv.y;
            float v2 = acc[i][j][2] + sbv.z;
            float v3 = acc[i][j][3] + sbv.w;
            if (LAST == 0) {
                v0 = v0 > 0.f ? v0 : __expf(v0) - 1.f;
                v1 = v1 > 0.f ? v1 : __expf(v1) - 1.f;
                v2 = v2 > 0.f ? v2 : __expf(v2) - 1.f;
                v3 = v3 > 0.f ? v3 : __expf(v3) - 1.f;
                ushort4 pk = {f2bf(v0), f2bf(v1), f2bf(v2), f2bf(v3)};
                *(ushort4*)(outb + (size_t)(b * 256 + nt * 128 + n) * 4096 + eh * Dq + o0) = pk;
            } else {
                ushort4 pk = {f2bf(v0), f2bf(v1), f2bf(v2), f2bf(v3)};
                *(ushort4*)(outb + ((size_t)eh * 4096 + b * 256 + nt * 128 + n) * Dq + o0) = pk;
            }
        }
    }
}

// ---------------------------------------------------------------------------
// K8: fused: st2[bn,o] = (1/32)*sum_eh h2b[eh,bn,o]; aw[bn] = sigmoid(st2.attW+attb)
__global__ __launch_bounds__(256) void reduce_aw_kernel(const bf16* __restrict__ h2b,
                                                        const float* __restrict__ attW,
                                                        const float* __restrict__ attb,
                                                        float* __restrict__ st2,
                                                        float* __restrict__ aw) {
    int t = threadIdx.x;
    int rl = t >> 7, o = t & 127;
    int r = blockIdx.x * 2 + rl;
    float acc = 0.f;
#pragma unroll
    for (int eh = 0; eh < EH; ++eh)
        acc += __bfloat162float(h2b[((size_t)eh * 4096 + r) * 128 + o]);
    acc *= (1.0f / 32.0f);
    st2[(size_t)r * 128 + o] = acc;
    float p = acc * attW[o];
#pragma unroll
    for (int off = 32; off; off >>= 1) p += __shfl_down(p, off);
    __shared__ float part[4];
    if ((t & 63) == 0) part[t >> 6] = p;
    __syncthreads();
    if (t == 0) aw[r] = 1.0f / (1.0f + __expf(-(part[0] + part[1] + attb[0])));
    if (t == 128) aw[r] = 1.0f / (1.0f + __expf(-(part[2] + part[3] + attb[0])));
}

// ---------------------------------------------------------------------------
// K10: out[b,d] = (1/256) * ( sum_o z[b,o]*outW[o,d] + sumaw[b]*outb[d] )
__global__ __launch_bounds__(128) void final_kernel(const float* __restrict__ st2,
                                                    const float* __restrict__ aw,
                                                    const float* __restrict__ outW,
                                                    const float* __restrict__ outb,
                                                    float* __restrict__ out) {
    int b = blockIdx.x;
    int t = threadIdx.x;
    __shared__ float awL[256], zL[128];
    awL[t] = aw[b * 256 + t];
    awL[t + 128] = aw[b * 256 + t + 128];
    __syncthreads();
    float z = 0.f;
    for (int n = 0; n < 256; ++n) z += awL[n] * st2[(size_t)(b * 256 + n) * Dq + t];
    float sa = 0.f;
    for (int n = 0; n < 256; ++n) sa += awL[n];
    zL[t] = z;
    __syncthreads();
    float acc = sa * outb[t];
    for (int o = 0; o < Dq; ++o) acc += zL[o] * outW[o * Dq + t];
    out[b * Dq + t] = acc * (1.0f / 256.0f);
}

// ---------------------------------------------------------------------------
extern "C" void kernel_launch(void* const* d_in, const int* in_sizes, int n_in,
                              void* d_out, int out_size, void* d_ws, size_t ws_size,
                              hipStream_t stream) {
    const int* nf = (const int*)d_in[0];
    const float* L = (const float*)d_in[1];
    const float* emb = (const float*)d_in[2];
    const float* W0 = (const float*)d_in[3];
    const float* W1 = (const float*)d_in[4];
    const float* a1w0 = (const float*)d_in[5];
    const float* a1b0 = (const float*)d_in[6];
    const float* a2w0 = (const float*)d_in[7];
    const float* a2b0 = (const float*)d_in[8];
    const float* a1w1 = (const float*)d_in[9];
    const float* a1b1 = (const float*)d_in[10];
    const float* a2w1 = (const float*)d_in[11];
    const float* a2b1 = (const float*)d_in[12];
    const float* sb0 = (const float*)d_in[13];
    const float* sb1 = (const float*)d_in[14];
    const float* outW = (const float*)d_in[15];
    const float* outb = (const float*)d_in[16];
    const float* attW = (const float*)d_in[17];
    const float* attb = (const float*)d_in[18];

    char* p = (char*)d_ws;
    bf16* st0b = (bf16*)(p);                        // [0, 1M)
    bf16* W0T  = (bf16*)(p + 1048576);              // [1M, 2M)
    bf16* W1T  = (bf16*)(p + 2097152);              // [2M, 34M)   dead after gemm1
    bf16* st1b = (bf16*)(p + 35651584);             // [34M, 66M)  dead after gemm1
    bf16* h2b  = (bf16*)(p + 2097152);              // [2M, 34M)   written by att1
    float* Le  = (float*)(p + 69206016);            // [66M, 82M)
    bf16* Wht  = (bf16*)(p + 85983232);             // [82M, 114M)
    float* s1  = (float*)(p + 119537664);           // 512K
    float* s2  = (float*)(p + 120061952);           // 512K
    float4* stat = (float4*)(p + 120586240);        // 2M
    float* st2 = (float*)(p);                       // reuse st0b/W0T (2 MB)
    float* aw  = s1;                                // reuse
    float* outp = (float*)d_out;

    prep_kernel<<<10368, 256, 0, stream>>>(nf, emb, W0, W1, L, st0b, W0T, W1T, Le);

    mfma_gemm_kernel<<<1024, 256, 0, stream>>>(st0b, W0T, Wht, a1w0, a1b0, a2w0, a2b0, s1, s2, 128);
    colsoft_kernel<<<dim3(8, 16, 4), 256, 0, stream>>>(s1, s2, Le, stat);
    att_mfma_kernel<0><<<dim3(2, 16, 32), 256, 0, stream>>>(s1, stat, Le, Wht, sb0, st1b);

    gemm4k_kernel<<<256, 512, 0, stream>>>(st1b, W1T, Wht, a1w1, a1b1, a2w1, a2b1, s1, s2);
    colsoft_kernel<<<dim3(8, 16, 4), 256, 0, stream>>>(s1, s2, Le, stat);
    att_mfma_kernel<1><<<dim3(2, 16, 32), 256, 0, stream>>>(s1, stat, Le, Wht, sb1, h2b);

    reduce_aw_kernel<<<2048, 256, 0, stream>>>(h2b, attW, attb, st2, aw);
    final_kernel<<<16, 128, 0, stream>>>(st2, aw, outW, outb, outp);
}

// Round 5
// 424.024 us; speedup vs baseline: 1.0404x; 1.0130x over previous
//
#include <hip/hip_runtime.h>
#include <hip/hip_bf16.h>

// Problem constants
#define Bq 16
#define Nq 256
#define E1q 4
#define Hq 8
#define Dq 128
#define EH 32
#define BN 4096

typedef __hip_bfloat16 bf16;
typedef short bf16x8 __attribute__((ext_vector_type(8)));
typedef float f32x4 __attribute__((ext_vector_type(4)));

__device__ __forceinline__ void gll16(const void* gptr, void* lptr) {
    __builtin_amdgcn_global_load_lds(
        (const __attribute__((address_space(1))) void*)gptr,
        (__attribute__((address_space(3))) void*)lptr, 16, 0, 0);
}

__device__ __forceinline__ unsigned short f2bf(float v) {
    __hip_bfloat16 h = __float2bfloat16(v);
    return *(unsigned short*)&h;
}

// ---------------------------------------------------------------------------
// K0: fused prep: gather st0b | transpose W0 | transpose W1 | pack Le
__device__ __forceinline__ void transpose_tile(const float* __restrict__ W,
                                               bf16* __restrict__ WT, int K,
                                               int kt, int nt, int eh,
                                               float (*tile)[65], int tid) {
    int tr = tid >> 6, tc = tid & 63;
    const float* src = W + ((size_t)eh * K + kt * 64) * 128 + nt * 64;
#pragma unroll
    for (int p = 0; p < 16; ++p) {
        int r = p * 4 + tr;
        tile[r][tc] = src[(size_t)r * 128 + tc];
    }
    __syncthreads();
    bf16* dst = WT + ((size_t)eh * 128 + nt * 64) * K + kt * 64;
#pragma unroll
    for (int p = 0; p < 16; ++p) {
        int n = p * 4 + tr;
        dst[(size_t)n * K + tc] = __float2bfloat16(tile[tc][n]);
    }
}

__global__ __launch_bounds__(256) void prep_kernel(const int* __restrict__ nf,
                                                   const float* __restrict__ emb,
                                                   const float* __restrict__ W0,
                                                   const float* __restrict__ W1,
                                                   const float* __restrict__ L,
                                                   bf16* __restrict__ st0b,
                                                   bf16* __restrict__ W0T,
                                                   bf16* __restrict__ W1T,
                                                   float* __restrict__ Le) {
    int bid = blockIdx.x;
    int t = threadIdx.x;
    __shared__ float tile[64][65];
    if (bid < 2048) {
        int i = bid * 256 + t;
        int row = i >> 7, col = i & 127;
        st0b[i] = __float2bfloat16(emb[nf[row] * Dq + col]);
    } else if (bid < 2176) {
        int id2 = bid - 2048;                       // (2 kt, 2 nt, 32 eh)
        transpose_tile(W0, W0T, 128, id2 & 1, (id2 >> 1) & 1, id2 >> 2, tile, t);
    } else if (bid < 6272) {
        int id3 = bid - 2176;                       // (64 kt, 2 nt, 32 eh)
        transpose_tile(W1, W1T, 4096, id3 & 63, (id3 >> 6) & 1, id3 >> 7, tile, t);
    } else {
        int idx = (bid - 6272) * 256 + t;           // 0..1048575
        float4 v = *(const float4*)(L + (size_t)idx * 4);
        Le[idx] = v.x;
        Le[1048576 + idx] = v.y;
        Le[2097152 + idx] = v.z;
        Le[3145728 + idx] = v.w;
    }
}

// ---------------------------------------------------------------------------
// K4: bf16 MFMA GEMM — LAYER 0 ONLY (K=128), 128-tile 2-barrier structure.
__global__ __launch_bounds__(256) void mfma_gemm_kernel(const bf16* __restrict__ Ab,
                                                        const bf16* __restrict__ Bt,
                                                        bf16* __restrict__ Wht,
                                                        const float* __restrict__ a1w,
                                                        const float* __restrict__ a1b,
                                                        const float* __restrict__ a2w,
                                                        const float* __restrict__ a2b,
                                                        float* __restrict__ s1,
                                                        float* __restrict__ s2, int K) {
    int id = blockIdx.x;
    int xcd = id & 7, slot = id >> 3;
    int eh = (slot & 3) * 8 + xcd;
    int rt = slot >> 2;
    int tid = threadIdx.x;
    int w = tid >> 6, l = tid & 63;
    int q = l >> 4, mn = l & 15;
    __shared__ __align__(16) bf16 As[128 * 64];
    __shared__ __align__(16) bf16 Bs[128 * 64];
    __shared__ float red1[128], red2[128];
    const bf16* Ap = Ab + (size_t)(rt * 128) * K;
    const bf16* Bp = Bt + (size_t)eh * 128 * K;
    int lr = l >> 3;                      // local row within 8-row chunk
    int g = (l & 7) ^ lr;                 // swizzled global k-quad for staging
    int gcol = g * 8;

    if (tid < 128) { red1[tid] = 0.f; red2[tid] = 0.f; }

    f32x4 acc[4][4];
#pragma unroll
    for (int i = 0; i < 4; i++)
#pragma unroll
        for (int j = 0; j < 4; j++) acc[i][j] = (f32x4){0.f, 0.f, 0.f, 0.f};

    int wr = (w >> 1) * 64, wc = (w & 1) * 64;
    int msw = mn & 7;

    for (int k0 = 0; k0 < K; k0 += 64) {
#pragma unroll
        for (int u = 0; u < 4; ++u) {
            int i = w * 4 + u;            // chunk 0..15
            int r = i * 8 + lr;
            gll16(Ap + (size_t)r * K + k0 + gcol, (char*)As + i * 1024);
            gll16(Bp + (size_t)r * K + k0 + gcol, (char*)Bs + i * 1024);
        }
        __syncthreads();
#pragma unroll
        for (int kk = 0; kk < 2; ++kk) {
            int qb = ((kk * 4 + q) ^ msw) * 16;
            bf16x8 af[4], bfr[4];
#pragma unroll
            for (int i = 0; i < 4; ++i) {
                af[i]  = *(const bf16x8*)((const char*)As + (wr + i * 16 + mn) * 128 + qb);
                bfr[i] = *(const bf16x8*)((const char*)Bs + (wc + i * 16 + mn) * 128 + qb);
            }
#pragma unroll
            for (int i = 0; i < 4; ++i)
#pragma unroll
                for (int j = 0; j < 4; ++j)
                    acc[i][j] = __builtin_amdgcn_mfma_f32_16x16x32_bf16(af[i], bfr[j], acc[i][j], 0, 0, 0);
        }
        __syncthreads();
    }
    // transposed bf16 store
#pragma unroll
    for (int i = 0; i < 4; ++i) {
        int r0 = rt * 128 + wr + i * 16 + q * 4;
        int b = r0 >> 8, m = r0 & 255;
#pragma unroll
        for (int j = 0; j < 4; ++j) {
            int o = wc + j * 16 + mn;
            ushort4 pk;
            pk.x = f2bf(acc[i][j][0]);
            pk.y = f2bf(acc[i][j][1]);
            pk.z = f2bf(acc[i][j][2]);
            pk.w = f2bf(acc[i][j][3]);
            *(ushort4*)(Wht + ((((size_t)eh * 16 + b) * 128 + o) * 256 + m)) = pk;
        }
    }
    // fused s1/s2
    float w1v[4], w2v[4];
#pragma unroll
    for (int j = 0; j < 4; ++j) {
        int o = wc + j * 16 + mn;
        w1v[j] = a1w[eh * 128 + o];
        w2v[j] = a2w[eh * 128 + o];
    }
#pragma unroll
    for (int i = 0; i < 4; ++i)
#pragma unroll
        for (int r = 0; r < 4; ++r) {
            float p1 = 0.f, p2 = 0.f;
#pragma unroll
            for (int j = 0; j < 4; ++j) {
                p1 += acc[i][j][r] * w1v[j];
                p2 += acc[i][j][r] * w2v[j];
            }
#pragma unroll
            for (int off = 1; off < 16; off <<= 1) {
                p1 += __shfl_xor(p1, off);
                p2 += __shfl_xor(p2, off);
            }
            if (mn == 0) {
                int row = wr + i * 16 + q * 4 + r;
                atomicAdd(&red1[row], p1);
                atomicAdd(&red2[row], p2);
            }
        }
    __syncthreads();
    if (tid < 128) {
        int rg = rt * 128 + tid;
        s1[eh * 4096 + rg] = red1[tid] + a1b[eh];
        s2[eh * 4096 + rg] = red2[tid] + a2b[eh];
    }
}

// ---------------------------------------------------------------------------
// K4b: LAYER-1 GEMM (4096^3 bf16), 256x256 tile — m201-exact port.
// R2/R3/R4 post-mortems: cross-tile register pipelines LOSE to the fine
// per-phase structure (m196). R1's per-phase form was best (141us); this
// round diffs R1 vs the verified m201 template and adopts its remaining
// elements: BK=64 double-buffer (2x64KB), 4 phases per K-tile with read
// cadence 12/8/4/0 (B-frag reuse: ph2 reuses Blo, ph4 reads nothing),
// half-tile staging (2 gll) per phase in read order {Alo,Blo,Ahi,Bhi},
// vmcnt(4) at ph1/ph2/ph4 ends only (each targets a stage issued 3 phases
// earlier; ledger verified), lgkm(8) pre-barrier on the 12-read phase.
// 128B LDS rows, phys 16B-slot = kq ^ (row&7) both-sides swizzle.
__global__ __launch_bounds__(512, 2) void gemm4k_kernel(const bf16* __restrict__ Ab,
                                                        const bf16* __restrict__ Bt,
                                                        bf16* __restrict__ Wht,
                                                        const float* __restrict__ a1w,
                                                        const float* __restrict__ a1b,
                                                        const float* __restrict__ a2w,
                                                        const float* __restrict__ a2b,
                                                        float* __restrict__ s1,
                                                        float* __restrict__ s2) {
    __shared__ __align__(16) char smem[131072];     // buf0: A[0,32K) B[32K,64K); buf1: +64K
    int bid = blockIdx.x;
    int wg = (bid & 7) * 32 + (bid >> 3);           // XCD-bijective (256 % 8 == 0)
    int tm = wg >> 4, tn = wg & 15;                 // tm: batch/row tile, tn: eh-pair
    int tid = threadIdx.x;
    int wid = tid >> 6, l = tid & 63;
    int wr = wid >> 2, wc = wid & 3;                // wave 2M x 4N
    int lhi = l >> 4, llo = l & 15;
    int skq = (l & 7) ^ ((l >> 3) & 7);             // stage-side pre-swizzled k-quad (8 slots)

    const bf16* Ap = Ab + (size_t)tm * 256 * 4096;
    const bf16* Bp = Bt + (size_t)tn * 256 * 4096;
    const bf16* sA = Ap + (size_t)(wid * 8 + (l >> 3)) * 4096 + skq * 8;
    const bf16* sB = Bp + (size_t)(wid * 8 + (l >> 3)) * 4096 + skq * 8;
    char* dA = (char*)smem + wid * 1024;            // wave-uniform LDS dests
    char* dB = (char*)smem + 32768 + wid * 1024;

    // stage op s=0..3: rows s*64..s*64+63 of the (A|B) panel, one gll16/thread
    auto stA = [&](int tt, int s) {
        gll16(sA + (size_t)s * 64 * 4096 + tt * 64, dA + (tt & 1) * 65536 + s * 8192);
    };
    auto stB = [&](int tt, int s) {
        gll16(sB + (size_t)s * 64 * 4096 + tt * 64, dB + (tt & 1) * 65536 + s * 8192);
    };

    f32x4 acc[8][4];
#pragma unroll
    for (int i = 0; i < 8; ++i)
#pragma unroll
        for (int j = 0; j < 4; ++j) acc[i][j] = (f32x4){0.f, 0.f, 0.f, 0.f};

    // read-side: row*128 bytes + phys-slot; phys = (ks*4+lhi) ^ (llo&7)
    int kp0 = ((lhi)     ^ (llo & 7)) << 4;         // ks=0 slot byte
    int kp1 = ((4 + lhi) ^ (llo & 7)) << 4;         // ks=1 slot byte
    int aoff = (wr * 64 + llo) << 7;                // A low base (mi: +mi*2048; high: +16384)
    int boff = 32768 + ((wc * 32 + llo) << 7);      // B low base (n: +n*2048; high: +16384)

    // prologue: tile 0 half-tiles in read order; Alo+Blo resident
    stA(0, 0); stA(0, 1); stB(0, 0); stB(0, 1);
    stA(0, 2); stA(0, 3); stB(0, 2); stB(0, 3);
    asm volatile("s_waitcnt vmcnt(4)" ::: "memory");
    __builtin_amdgcn_s_barrier();

#pragma unroll 1
    for (int t = 0; t < 64; ++t) {
        const char* sm = (const char*)smem + (t & 1) * 65536;
        bf16x8 A0[4][2], A1[4][2], B0[2][2], B1[2][2];
        // ---- ph1: read A-lo(8)+B-lo(4); stage Alo(t+1); MFMA m0-3 x n0-1 ----
#pragma unroll
        for (int m = 0; m < 4; ++m) {
            A0[m][0] = *(const bf16x8*)(sm + aoff + m * 2048 + kp0);
            A0[m][1] = *(const bf16x8*)(sm + aoff + m * 2048 + kp1);
        }
#pragma unroll
        for (int n = 0; n < 2; ++n) {
            B0[n][0] = *(const bf16x8*)(sm + boff + n * 2048 + kp0);
            B0[n][1] = *(const bf16x8*)(sm + boff + n * 2048 + kp1);
        }
        if (t < 63) { stA(t + 1, 0); stA(t + 1, 1); }
        asm volatile("s_waitcnt lgkmcnt(8)" ::: "memory");
        __builtin_amdgcn_s_barrier();
        asm volatile("s_waitcnt lgkmcnt(0)" ::: "memory");
        __builtin_amdgcn_sched_barrier(0);
        __builtin_amdgcn_s_setprio(1);
#pragma unroll
        for (int ks = 0; ks < 2; ++ks)
#pragma unroll
            for (int m = 0; m < 4; ++m)
#pragma unroll
                for (int n = 0; n < 2; ++n)
                    acc[m][n] = __builtin_amdgcn_mfma_f32_16x16x32_bf16(A0[m][ks], B0[n][ks], acc[m][n], 0, 0, 0);
        __builtin_amdgcn_s_setprio(0);
        if (t < 63) { asm volatile("s_waitcnt vmcnt(4)" ::: "memory"); }
        else        { asm volatile("s_waitcnt vmcnt(2)" ::: "memory"); }
        __builtin_amdgcn_s_barrier();
        // ---- ph2: read A-hi(8); stage Blo(t+1); MFMA m4-7 x n0-1 (B reuse) ----
#pragma unroll
        for (int m = 0; m < 4; ++m) {
            A1[m][0] = *(const bf16x8*)(sm + aoff + 16384 + m * 2048 + kp0);
            A1[m][1] = *(const bf16x8*)(sm + aoff + 16384 + m * 2048 + kp1);
        }
        if (t < 63) { stB(t + 1, 0); stB(t + 1, 1); }
        __builtin_amdgcn_s_barrier();
        asm volatile("s_waitcnt lgkmcnt(0)" ::: "memory");
        __builtin_amdgcn_sched_barrier(0);
        __builtin_amdgcn_s_setprio(1);
#pragma unroll
        for (int ks = 0; ks < 2; ++ks)
#pragma unroll
            for (int m = 0; m < 4; ++m)
#pragma unroll
                for (int n = 0; n < 2; ++n)
                    acc[4 + m][n] = __builtin_amdgcn_mfma_f32_16x16x32_bf16(A1[m][ks], B0[n][ks], acc[4 + m][n], 0, 0, 0);
        __builtin_amdgcn_s_setprio(0);
        if (t < 63) { asm volatile("s_waitcnt vmcnt(4)" ::: "memory"); }
        else        { asm volatile("s_waitcnt vmcnt(0)" ::: "memory"); }
        __builtin_amdgcn_s_barrier();
        // ---- ph3: read B-hi(4); stage Ahi(t+1); MFMA m0-3 x n2-3 (A0 reuse) ----
#pragma unroll
        for (int n = 0; n < 2; ++n) {
            B1[n][0] = *(const bf16x8*)(sm + boff + 16384 + n * 2048 + kp0);
            B1[n][1] = *(const bf16x8*)(sm + boff + 16384 + n * 2048 + kp1);
        }
        if (t < 63) { stA(t + 1, 2); stA(t + 1, 3); }
        __builtin_amdgcn_s_barrier();
        asm volatile("s_waitcnt lgkmcnt(0)" ::: "memory");
        __builtin_amdgcn_sched_barrier(0);
        __builtin_amdgcn_s_setprio(1);
#pragma unroll
        for (int ks = 0; ks < 2; ++ks)
#pragma unroll
            for (int m = 0; m < 4; ++m)
#pragma unroll
                for (int n = 0; n < 2; ++n)
                    acc[m][2 + n] = __builtin_amdgcn_mfma_f32_16x16x32_bf16(A0[m][ks], B1[n][ks], acc[m][2 + n], 0, 0, 0);
        __builtin_amdgcn_s_setprio(0);
        __builtin_amdgcn_s_barrier();               // no vmcnt (ph4 reads nothing)
        // ---- ph4: stage Bhi(t+1); MFMA m4-7 x n2-3 (all regs); 1 barrier ----
        if (t < 63) { stB(t + 1, 2); stB(t + 1, 3); }
        __builtin_amdgcn_s_setprio(1);
#pragma unroll
        for (int ks = 0; ks < 2; ++ks)
#pragma unroll
            for (int m = 0; m < 4; ++m)
#pragma unroll
                for (int n = 0; n < 2; ++n)
                    acc[4 + m][2 + n] = __builtin_amdgcn_mfma_f32_16x16x32_bf16(A1[m][ks], B1[n][ks], acc[4 + m][2 + n], 0, 0, 0);
        __builtin_amdgcn_s_setprio(0);
        if (t < 63) { asm volatile("s_waitcnt vmcnt(4)" ::: "memory"); }
        __builtin_amdgcn_s_barrier();
    }

    // ---- epilogue: transposed Wht store + fused s1/s2 (2 eh per block) ----
    float* red = (float*)smem;                      // 1024 floats, LDS reuse
    red[tid] = 0.f;
    red[tid + 512] = 0.f;
    float w1v[4], w2v[4];
#pragma unroll
    for (int n = 0; n < 4; ++n) {
        int eh = tn * 2 + (n >> 1);
        int o = wc * 32 + (n & 1) * 16 + llo;
        w1v[n] = a1w[eh * 128 + o];
        w2v[n] = a2w[eh * 128 + o];
    }
    __syncthreads();
#pragma unroll
    for (int mi = 0; mi < 8; ++mi) {
        int R = (mi >> 2) * 128 + wr * 64 + (mi & 3) * 16 + lhi * 4;
#pragma unroll
        for (int n = 0; n < 4; ++n) {
            int eh = tn * 2 + (n >> 1);
            int o = wc * 32 + (n & 1) * 16 + llo;
            ushort4 pk;
            pk.x = f2bf(acc[mi][n][0]);
            pk.y = f2bf(acc[mi][n][1]);
            pk.z = f2bf(acc[mi][n][2]);
            pk.w = f2bf(acc[mi][n][3]);
            *(ushort4*)(Wht + ((((size_t)eh * 16 + tm) * 128 + o) * 256 + R)) = pk;
        }
#pragma unroll
        for (int r = 0; r < 4; ++r) {
            float p10 = acc[mi][0][r] * w1v[0] + acc[mi][1][r] * w1v[1];
            float p11 = acc[mi][2][r] * w1v[2] + acc[mi][3][r] * w1v[3];
            float p20 = acc[mi][0][r] * w2v[0] + acc[mi][1][r] * w2v[1];
            float p21 = acc[mi][2][r] * w2v[2] + acc[mi][3][r] * w2v[3];
#pragma unroll
            for (int off = 1; off < 16; off <<= 1) {
                p10 += __shfl_xor(p10, off);
                p11 += __shfl_xor(p11, off);
                p20 += __shfl_xor(p20, off);
                p21 += __shfl_xor(p21, off);
            }
            if (llo == 0) {
                int row = R + r;
                atomicAdd(&red[row], p10);
                atomicAdd(&red[256 + row], p11);
                atomicAdd(&red[512 + row], p20);
                atomicAdd(&red[768 + row], p21);
            }
        }
    }
    __syncthreads();
    {
        int ehl = tid >> 8, row = tid & 255;
        int eh = tn * 2 + ehl;
        s1[eh * 4096 + tm * 256 + row] = red[ehl * 256 + row] + a1b[eh];
        s2[eh * 4096 + tm * 256 + row] = red[512 + ehl * 256 + row] + a2b[eh];
    }
}

// ---------------------------------------------------------------------------
// K6: column softmax stats, SINGLE PASS with analytic bound (shift-invariant:
// any bound >= max works; bound = leaky(s1max+s2)+8 covers |L|max for randn).
// Writes packed stat[m] = {s2, bound, cinv, 0}.
__global__ __launch_bounds__(256) void colsoft_kernel(const float* __restrict__ s1,
                                                      const float* __restrict__ s2,
                                                      const float* __restrict__ Le,
                                                      float4* __restrict__ stat) {
    int mt = blockIdx.x, b = blockIdx.y, e = blockIdx.z;
    int t = threadIdx.x;
    __shared__ float Lt[256 * 32];
    __shared__ float s1L[8 * 256];
#pragma unroll
    for (int i = 0; i < 8; ++i) s1L[i * 256 + t] = s1[(e * 8 + i) * 4096 + b * 256 + t];
    const float* Lb = Le + ((size_t)(e * 16 + b) * 256) * 256 + mt * 32;
#pragma unroll
    for (int j = 0; j < 8; ++j) {
        int f = t + 256 * j;
        int n = f >> 3, c4 = (f & 7) * 4;
        *(float4*)(Lt + n * 32 + c4) = *(const float4*)(Lb + (size_t)n * 256 + c4);
    }
    __syncthreads();
    int h = t >> 5, mm = t & 31;
    int m = mt * 32 + mm;
    float s2v = s2[(e * 8 + h) * 4096 + b * 256 + m];
    const float* s1p = s1L + h * 256;
    // s1max over 256: 8 per thread + shuffle over the 32-lane half-wave
    float s1max = -1e30f;
#pragma unroll
    for (int u = 0; u < 8; ++u) s1max = fmaxf(s1max, s1p[mm * 8 + u]);
#pragma unroll
    for (int off = 16; off; off >>= 1) s1max = fmaxf(s1max, __shfl_xor(s1max, off));
    float sm = s1max + s2v;
    float bound = (sm > 0.f ? sm : 0.2f * sm) + 8.0f;
    float sum = 0.f;
    for (int n = 0; n < 256; ++n) {
        float x = s1p[n] + s2v;
        x = x > 0.f ? x : 0.2f * x;
        x += Lt[n * 32 + mm];
        sum += __expf(x - bound);
    }
    float4 st = {s2v, bound, 1.0f / sum, 0.f};
    stat[(e * 8 + h) * 4096 + b * 256 + m] = st;
}

// ---------------------------------------------------------------------------
// K7: MFMA att-apply. Per (nt,b,eh): D[o][n] = sum_m Wht[o][m]*att[n][m]
// L loads software-pipelined: iter k+1's 4 float4s issue before iter k's MFMA.
// LAST=0: st1b bf16 elu; LAST=1: h2 bf16 (no elu)
template <int LAST>
__global__ __launch_bounds__(256) void att_mfma_kernel(const float* __restrict__ s1,
                                                       const float4* __restrict__ stat,
                                                       const float* __restrict__ Le,
                                                       const bf16* __restrict__ Wht,
                                                       const float* __restrict__ sb,
                                                       bf16* __restrict__ outb) {
    int nt = blockIdx.x;   // 0..1
    int b = blockIdx.y;    // 0..15
    int eh = blockIdx.z;   // 0..31
    int e = eh >> 3;
    int tid = threadIdx.x;
    int w = tid >> 6, l = tid & 63;
    int q = l >> 4, mn = l & 15;
    __shared__ __align__(16) bf16 As[128 * 32];
    __shared__ __align__(16) bf16 Bs[128 * 40];   // att rows padded 32->40
    __shared__ float s1L[128];
    __shared__ __align__(16) float4 stL[256];

    int base = eh * 4096 + b * 256;
    if (tid < 128) s1L[tid] = s1[base + nt * 128 + tid];
    stL[tid] = stat[base + tid];
    __syncthreads();

    const bf16* Whtp = Wht + ((size_t)eh * 16 + b) * 32768;
    int nl = tid >> 1, mh = (tid & 1) * 16;
    const float* Lrow = Le + (((size_t)(e * 16 + b) * 256) + nt * 128 + nl) * 256;
    float s1v = s1L[nl];
    int srow = l >> 2;
    int sq = (l & 3) ^ ((l >> 3) & 3);
    int scol = sq * 8;
    int rsw = ((mn >> 1) & 3) << 3;

    f32x4 acc[4][4];
#pragma unroll
    for (int i = 0; i < 4; i++)
#pragma unroll
        for (int j = 0; j < 4; j++) acc[i][j] = (f32x4){0.f, 0.f, 0.f, 0.f};

    int wr = (w >> 1) * 64, wc = (w & 1) * 64;

    // prefetch L for iteration 0
    float4 lv[4];
#pragma unroll
    for (int jj = 0; jj < 4; ++jj) lv[jj] = *(const float4*)(Lrow + mh + jj * 4);

    for (int k0 = 0; k0 < 256; k0 += 32) {
#pragma unroll
        for (int u = 0; u < 2; ++u) {
            int i = 2 * w + u;
            gll16(Whtp + (size_t)(i * 16 + srow) * 256 + k0 + scol, (char*)As + i * 1024);
        }
        float4 cur[4];
#pragma unroll
        for (int jj = 0; jj < 4; ++jj) cur[jj] = lv[jj];
        if (k0 + 32 < 256) {
#pragma unroll
            for (int jj = 0; jj < 4; ++jj)
                lv[jj] = *(const float4*)(Lrow + k0 + 32 + mh + jj * 4);
        }
#pragma unroll
        for (int jj = 0; jj < 4; ++jj) {
            int mb = mh + jj * 4;
            float av[4];
#pragma unroll
            for (int c = 0; c < 4; ++c) {
                int m = k0 + mb + c;
                float4 stv = stL[m];
                float x = s1v + stv.x;
                x = x > 0.f ? x : 0.2f * x;
                x += ((const float*)&cur[jj])[c];
                av[c] = __expf(x - stv.y) * stv.z;
            }
            unsigned int u01 = (unsigned int)f2bf(av[0]) | ((unsigned int)f2bf(av[1]) << 16);
            unsigned int u23 = (unsigned int)f2bf(av[2]) | ((unsigned int)f2bf(av[3]) << 16);
            unsigned int* bp = (unsigned int*)Bs + (nl * 40 + mb) / 2;
            bp[0] = u01;
            bp[1] = u23;
        }
        __syncthreads();
        bf16x8 af[4], bfr[4];
#pragma unroll
        for (int i = 0; i < 4; ++i) {
            af[i]  = *(const bf16x8*)(As + (wr + i * 16 + mn) * 32 + ((q << 3) ^ rsw));
            bfr[i] = *(const bf16x8*)(Bs + (wc + i * 16 + mn) * 40 + q * 8);
        }
#pragma unroll
        for (int i = 0; i < 4; ++i)
#pragma unroll
            for (int j = 0; j < 4; ++j)
                acc[i][j] = __builtin_amdgcn_mfma_f32_16x16x32_bf16(af[i], bfr[j], acc[i][j], 0, 0, 0);
        __syncthreads();
    }
#pragma unroll
    for (int i = 0; i < 4; ++i) {
        int o0 = wr + i * 16 + q * 4;
        float4 sbv = *(const float4*)(sb + eh * 128 + o0);
#pragma unroll
        for (int j = 0; j < 4; ++j) {
            int n = wc + j * 16 + mn;
            float v0 = acc[i][j][0] + sbv.x;
            float v1 = acc[i][j][1] + sbv.y;
            float v2 = acc[i][j][2] + sbv.z;
            float v3 = acc[i][j][3] + sbv.w;
            if (LAST == 0) {
                v0 = v0 > 0.f ? v0 : __expf(v0) - 1.f;
                v1 = v1 > 0.f ? v1 : __expf(v1) - 1.f;
                v2 = v2 > 0.f ? v2 : __expf(v2) - 1.f;
                v3 = v3 > 0.f ? v3 : __expf(v3) - 1.f;
                ushort4 pk = {f2bf(v0), f2bf(v1), f2bf(v2), f2bf(v3)};
                *(ushort4*)(outb + (size_t)(b * 256 + nt * 128 + n) * 4096 + eh * Dq + o0) = pk;
            } else {
                ushort4 pk = {f2bf(v0), f2bf(v1), f2bf(v2), f2bf(v3)};
                *(ushort4*)(outb + ((size_t)eh * 4096 + b * 256 + nt * 128 + n) * Dq + o0) = pk;
            }
        }
    }
}

// ---------------------------------------------------------------------------
// K8: fused: st2[bn,o] = (1/32)*sum_eh h2b[eh,bn,o]; aw[bn] = sigmoid(st2.attW+attb)
__global__ __launch_bounds__(256) void reduce_aw_kernel(const bf16* __restrict__ h2b,
                                                        const float* __restrict__ attW,
                                                        const float* __restrict__ attb,
                                                        float* __restrict__ st2,
                                                        float* __restrict__ aw) {
    int t = threadIdx.x;
    int rl = t >> 7, o = t & 127;
    int r = blockIdx.x * 2 + rl;
    float acc = 0.f;
#pragma unroll
    for (int eh = 0; eh < EH; ++eh)
        acc += __bfloat162float(h2b[((size_t)eh * 4096 + r) * 128 + o]);
    acc *= (1.0f / 32.0f);
    st2[(size_t)r * 128 + o] = acc;
    float p = acc * attW[o];
#pragma unroll
    for (int off = 32; off; off >>= 1) p += __shfl_down(p, off);
    __shared__ float part[4];
    if ((t & 63) == 0) part[t >> 6] = p;
    __syncthreads();
    if (t == 0) aw[r] = 1.0f / (1.0f + __expf(-(part[0] + part[1] + attb[0])));
    if (t == 128) aw[r] = 1.0f / (1.0f + __expf(-(part[2] + part[3] + attb[0])));
}

// ---------------------------------------------------------------------------
// K10: out[b,d] = (1/256) * ( sum_o z[b,o]*outW[o,d] + sumaw[b]*outb[d] )
__global__ __launch_bounds__(128) void final_kernel(const float* __restrict__ st2,
                                                    const float* __restrict__ aw,
                                                    const float* __restrict__ outW,
                                                    const float* __restrict__ outb,
                                                    float* __restrict__ out) {
    int b = blockIdx.x;
    int t = threadIdx.x;
    __shared__ float awL[256], zL[128];
    awL[t] = aw[b * 256 + t];
    awL[t + 128] = aw[b * 256 + t + 128];
    __syncthreads();
    float z = 0.f;
    for (int n = 0; n < 256; ++n) z += awL[n] * st2[(size_t)(b * 256 + n) * Dq + t];
    float sa = 0.f;
    for (int n = 0; n < 256; ++n) sa += awL[n];
    zL[t] = z;
    __syncthreads();
    float acc = sa * outb[t];
    for (int o = 0; o < Dq; ++o) acc += zL[o] * outW[o * Dq + t];
    out[b * Dq + t] = acc * (1.0f / 256.0f);
}

// ---------------------------------------------------------------------------
extern "C" void kernel_launch(void* const* d_in, const int* in_sizes, int n_in,
                              void* d_out, int out_size, void* d_ws, size_t ws_size,
                              hipStream_t stream) {
    const int* nf = (const int*)d_in[0];
    const float* L = (const float*)d_in[1];
    const float* emb = (const float*)d_in[2];
    const float* W0 = (const float*)d_in[3];
    const float* W1 = (const float*)d_in[4];
    const float* a1w0 = (const float*)d_in[5];
    const float* a1b0 = (const float*)d_in[6];
    const float* a2w0 = (const float*)d_in[7];
    const float* a2b0 = (const float*)d_in[8];
    const float* a1w1 = (const float*)d_in[9];
    const float* a1b1 = (const float*)d_in[10];
    const float* a2w1 = (const float*)d_in[11];
    const float* a2b1 = (const float*)d_in[12];
    const float* sb0 = (const float*)d_in[13];
    const float* sb1 = (const float*)d_in[14];
    const float* outW = (const float*)d_in[15];
    const float* outb = (const float*)d_in[16];
    const float* attW = (const float*)d_in[17];
    const float* attb = (const float*)d_in[18];

    char* p = (char*)d_ws;
    bf16* st0b = (bf16*)(p);                        // [0, 1M)
    bf16* W0T  = (bf16*)(p + 1048576);              // [1M, 2M)
    bf16* W1T  = (bf16*)(p + 2097152);              // [2M, 34M)   dead after gemm1
    bf16* st1b = (bf16*)(p + 35651584);             // [34M, 66M)  dead after gemm1
    bf16* h2b  = (bf16*)(p + 2097152);              // [2M, 34M)   written by att1
    float* Le  = (float*)(p + 69206016);            // [66M, 82M)
    bf16* Wht  = (bf16*)(p + 85983232);             // [82M, 114M)
    float* s1  = (float*)(p + 119537664);           // 512K
    float* s2  = (float*)(p + 120061952);           // 512K
    float4* stat = (float4*)(p + 120586240);        // 2M
    float* st2 = (float*)(p);                       // reuse st0b/W0T (2 MB)
    float* aw  = s1;                                // reuse
    float* outp = (float*)d_out;

    prep_kernel<<<10368, 256, 0, stream>>>(nf, emb, W0, W1, L, st0b, W0T, W1T, Le);

    mfma_gemm_kernel<<<1024, 256, 0, stream>>>(st0b, W0T, Wht, a1w0, a1b0, a2w0, a2b0, s1, s2, 128);
    colsoft_kernel<<<dim3(8, 16, 4), 256, 0, stream>>>(s1, s2, Le, stat);
    att_mfma_kernel<0><<<dim3(2, 16, 32), 256, 0, stream>>>(s1, stat, Le, Wht, sb0, st1b);

    gemm4k_kernel<<<256, 512, 0, stream>>>(st1b, W1T, Wht, a1w1, a1b1, a2w1, a2b1, s1, s2);
    colsoft_kernel<<<dim3(8, 16, 4), 256, 0, stream>>>(s1, s2, Le, stat);
    att_mfma_kernel<1><<<dim3(2, 16, 32), 256, 0, stream>>>(s1, stat, Le, Wht, sb1, h2b);

    reduce_aw_kernel<<<2048, 256, 0, stream>>>(h2b, attW, attb, st2, aw);
    final_kernel<<<16, 128, 0, stream>>>(st2, aw, outW, outb, outp);
}

// Round 6
// 411.626 us; speedup vs baseline: 1.0717x; 1.0301x over previous
//
#include <hip/hip_runtime.h>
#include <hip/hip_bf16.h>

// Problem constants
#define Bq 16
#define Nq 256
#define E1q 4
#define Hq 8
#define Dq 128
#define EH 32
#define BN 4096

typedef __hip_bfloat16 bf16;
typedef short bf16x8 __attribute__((ext_vector_type(8)));
typedef float f32x4 __attribute__((ext_vector_type(4)));

__device__ __forceinline__ void gll16(const void* gptr, void* lptr) {
    __builtin_amdgcn_global_load_lds(
        (const __attribute__((address_space(1))) void*)gptr,
        (__attribute__((address_space(3))) void*)lptr, 16, 0, 0);
}

__device__ __forceinline__ unsigned short f2bf(float v) {
    __hip_bfloat16 h = __float2bfloat16(v);
    return *(unsigned short*)&h;
}

// ---------------------------------------------------------------------------
// K0: fused prep: gather st0b | transpose W0 | transpose W1 | pack Le
__device__ __forceinline__ void transpose_tile(const float* __restrict__ W,
                                               bf16* __restrict__ WT, int K,
                                               int kt, int nt, int eh,
                                               float (*tile)[65], int tid) {
    int tr = tid >> 6, tc = tid & 63;
    const float* src = W + ((size_t)eh * K + kt * 64) * 128 + nt * 64;
#pragma unroll
    for (int p = 0; p < 16; ++p) {
        int r = p * 4 + tr;
        tile[r][tc] = src[(size_t)r * 128 + tc];
    }
    __syncthreads();
    bf16* dst = WT + ((size_t)eh * 128 + nt * 64) * K + kt * 64;
#pragma unroll
    for (int p = 0; p < 16; ++p) {
        int n = p * 4 + tr;
        dst[(size_t)n * K + tc] = __float2bfloat16(tile[tc][n]);
    }
}

__global__ __launch_bounds__(256) void prep_kernel(const int* __restrict__ nf,
                                                   const float* __restrict__ emb,
                                                   const float* __restrict__ W0,
                                                   const float* __restrict__ W1,
                                                   const float* __restrict__ L,
                                                   bf16* __restrict__ st0b,
                                                   bf16* __restrict__ W0T,
                                                   bf16* __restrict__ W1T,
                                                   float* __restrict__ Le) {
    int bid = blockIdx.x;
    int t = threadIdx.x;
    __shared__ float tile[64][65];
    if (bid < 2048) {
        int i = bid * 256 + t;
        int row = i >> 7, col = i & 127;
        st0b[i] = __float2bfloat16(emb[nf[row] * Dq + col]);
    } else if (bid < 2176) {
        int id2 = bid - 2048;                       // (2 kt, 2 nt, 32 eh)
        transpose_tile(W0, W0T, 128, id2 & 1, (id2 >> 1) & 1, id2 >> 2, tile, t);
    } else if (bid < 6272) {
        int id3 = bid - 2176;                       // (64 kt, 2 nt, 32 eh)
        transpose_tile(W1, W1T, 4096, id3 & 63, (id3 >> 6) & 1, id3 >> 7, tile, t);
    } else {
        int idx = (bid - 6272) * 256 + t;           // 0..1048575
        float4 v = *(const float4*)(L + (size_t)idx * 4);
        Le[idx] = v.x;
        Le[1048576 + idx] = v.y;
        Le[2097152 + idx] = v.z;
        Le[3145728 + idx] = v.w;
    }
}

// ---------------------------------------------------------------------------
// K4: bf16 MFMA GEMM — LAYER 0 ONLY (K=128), 128-tile 2-barrier structure.
__global__ __launch_bounds__(256) void mfma_gemm_kernel(const bf16* __restrict__ Ab,
                                                        const bf16* __restrict__ Bt,
                                                        bf16* __restrict__ Wht,
                                                        const float* __restrict__ a1w,
                                                        const float* __restrict__ a1b,
                                                        const float* __restrict__ a2w,
                                                        const float* __restrict__ a2b,
                                                        float* __restrict__ s1,
                                                        float* __restrict__ s2, int K) {
    int id = blockIdx.x;
    int xcd = id & 7, slot = id >> 3;
    int eh = (slot & 3) * 8 + xcd;
    int rt = slot >> 2;
    int tid = threadIdx.x;
    int w = tid >> 6, l = tid & 63;
    int q = l >> 4, mn = l & 15;
    __shared__ __align__(16) bf16 As[128 * 64];
    __shared__ __align__(16) bf16 Bs[128 * 64];
    __shared__ float red1[128], red2[128];
    const bf16* Ap = Ab + (size_t)(rt * 128) * K;
    const bf16* Bp = Bt + (size_t)eh * 128 * K;
    int lr = l >> 3;                      // local row within 8-row chunk
    int g = (l & 7) ^ lr;                 // swizzled global k-quad for staging
    int gcol = g * 8;

    if (tid < 128) { red1[tid] = 0.f; red2[tid] = 0.f; }

    f32x4 acc[4][4];
#pragma unroll
    for (int i = 0; i < 4; i++)
#pragma unroll
        for (int j = 0; j < 4; j++) acc[i][j] = (f32x4){0.f, 0.f, 0.f, 0.f};

    int wr = (w >> 1) * 64, wc = (w & 1) * 64;
    int msw = mn & 7;

    for (int k0 = 0; k0 < K; k0 += 64) {
#pragma unroll
        for (int u = 0; u < 4; ++u) {
            int i = w * 4 + u;            // chunk 0..15
            int r = i * 8 + lr;
            gll16(Ap + (size_t)r * K + k0 + gcol, (char*)As + i * 1024);
            gll16(Bp + (size_t)r * K + k0 + gcol, (char*)Bs + i * 1024);
        }
        __syncthreads();
#pragma unroll
        for (int kk = 0; kk < 2; ++kk) {
            int qb = ((kk * 4 + q) ^ msw) * 16;
            bf16x8 af[4], bfr[4];
#pragma unroll
            for (int i = 0; i < 4; ++i) {
                af[i]  = *(const bf16x8*)((const char*)As + (wr + i * 16 + mn) * 128 + qb);
                bfr[i] = *(const bf16x8*)((const char*)Bs + (wc + i * 16 + mn) * 128 + qb);
            }
#pragma unroll
            for (int i = 0; i < 4; ++i)
#pragma unroll
                for (int j = 0; j < 4; ++j)
                    acc[i][j] = __builtin_amdgcn_mfma_f32_16x16x32_bf16(af[i], bfr[j], acc[i][j], 0, 0, 0);
        }
        __syncthreads();
    }
    // transposed bf16 store
#pragma unroll
    for (int i = 0; i < 4; ++i) {
        int r0 = rt * 128 + wr + i * 16 + q * 4;
        int b = r0 >> 8, m = r0 & 255;
#pragma unroll
        for (int j = 0; j < 4; ++j) {
            int o = wc + j * 16 + mn;
            ushort4 pk;
            pk.x = f2bf(acc[i][j][0]);
            pk.y = f2bf(acc[i][j][1]);
            pk.z = f2bf(acc[i][j][2]);
            pk.w = f2bf(acc[i][j][3]);
            *(ushort4*)(Wht + ((((size_t)eh * 16 + b) * 128 + o) * 256 + m)) = pk;
        }
    }
    // fused s1/s2
    float w1v[4], w2v[4];
#pragma unroll
    for (int j = 0; j < 4; ++j) {
        int o = wc + j * 16 + mn;
        w1v[j] = a1w[eh * 128 + o];
        w2v[j] = a2w[eh * 128 + o];
    }
#pragma unroll
    for (int i = 0; i < 4; ++i)
#pragma unroll
        for (int r = 0; r < 4; ++r) {
            float p1 = 0.f, p2 = 0.f;
#pragma unroll
            for (int j = 0; j < 4; ++j) {
                p1 += acc[i][j][r] * w1v[j];
                p2 += acc[i][j][r] * w2v[j];
            }
#pragma unroll
            for (int off = 1; off < 16; off <<= 1) {
                p1 += __shfl_xor(p1, off);
                p2 += __shfl_xor(p2, off);
            }
            if (mn == 0) {
                int row = wr + i * 16 + q * 4 + r;
                atomicAdd(&red1[row], p1);
                atomicAdd(&red2[row], p2);
            }
        }
    __syncthreads();
    if (tid < 128) {
        int rg = rt * 128 + tid;
        s1[eh * 4096 + rg] = red1[tid] + a1b[eh];
        s2[eh * 4096 + rg] = red2[tid] + a2b[eh];
    }
}

// ---------------------------------------------------------------------------
// K4b: LAYER-1 GEMM (4096^3 bf16), 256x256, BK=64 double-buffer, 4 phases.
// R5 post-mortem: per-tile MFMA=2483cyc + LDS=2304cyc were SERIALIZED because
// each phase lgkm(0)-waited its OWN reads. Fix: reads shifted ONE PHASE EARLY
// with counted lgkm so they drain under the previous MFMA cluster:
//   read-issue: ph4 -> A0,B0(t+1) (12); ph1 -> A1 (8); ph2 -> B1 (4); ph3: 0
//   lgkm:       ph1 (8)             ph2 (4)       ph3 (0)       ph4: none
// A0,B0 are loop-carried registers (single live range, no rotation movs —
// the R3 trap). Stages unchanged (2 gll/phase: Alo,Blo,Ahi,Bhi of t+1);
// vmcnt(2)+barrier at ph1/ph3/ph4 ends only (each targets a stage >=2 phases
// old); ph2 has no barrier. 3 barriers/tile (was 7). Ledger:
//   ph3-end vm(2): Alo,Blo(t+1) done -> ph4's A0,B0 reads OK
//   ph4-end vm(2): Ahi(t+1) done    -> ph1's A1 reads OK
//   ph1-end vm(2): Bhi(t)  done     -> ph2's B1 reads OK
// Prologue: stage tile0 (8); vm(4); barrier; read A0,B0; vm(2); barrier.
__global__ __launch_bounds__(512, 2) void gemm4k_kernel(const bf16* __restrict__ Ab,
                                                        const bf16* __restrict__ Bt,
                                                        bf16* __restrict__ Wht,
                                                        const float* __restrict__ a1w,
                                                        const float* __restrict__ a1b,
                                                        const float* __restrict__ a2w,
                                                        const float* __restrict__ a2b,
                                                        float* __restrict__ s1,
                                                        float* __restrict__ s2) {
    __shared__ __align__(16) char smem[131072];     // buf0: A[0,32K) B[32K,64K); buf1: +64K
    int bid = blockIdx.x;
    int wg = (bid & 7) * 32 + (bid >> 3);           // XCD-bijective (256 % 8 == 0)
    int tm = wg >> 4, tn = wg & 15;                 // tm: batch/row tile, tn: eh-pair
    int tid = threadIdx.x;
    int wid = tid >> 6, l = tid & 63;
    int wr = wid >> 2, wc = wid & 3;                // wave 2M x 4N
    int lhi = l >> 4, llo = l & 15;
    int skq = (l & 7) ^ ((l >> 3) & 7);             // stage-side pre-swizzled k-quad

    const bf16* Ap = Ab + (size_t)tm * 256 * 4096;
    const bf16* Bp = Bt + (size_t)tn * 256 * 4096;
    const bf16* sA = Ap + (size_t)(wid * 8 + (l >> 3)) * 4096 + skq * 8;
    const bf16* sB = Bp + (size_t)(wid * 8 + (l >> 3)) * 4096 + skq * 8;
    char* dA = (char*)smem + wid * 1024;            // wave-uniform LDS dests
    char* dB = (char*)smem + 32768 + wid * 1024;

    auto stA = [&](int tt, int s) {
        gll16(sA + (size_t)s * 64 * 4096 + tt * 64, dA + (tt & 1) * 65536 + s * 8192);
    };
    auto stB = [&](int tt, int s) {
        gll16(sB + (size_t)s * 64 * 4096 + tt * 64, dB + (tt & 1) * 65536 + s * 8192);
    };

    f32x4 acc[8][4];
#pragma unroll
    for (int i = 0; i < 8; ++i)
#pragma unroll
        for (int j = 0; j < 4; ++j) acc[i][j] = (f32x4){0.f, 0.f, 0.f, 0.f};

    // read-side: phys 16B slot = (ks*4+lhi) ^ (llo&7), 128B rows
    int kp0 = ((lhi)     ^ (llo & 7)) << 4;
    int kp1 = ((4 + lhi) ^ (llo & 7)) << 4;
    int aoff = (wr * 64 + llo) << 7;                // A low base
    int boff = 32768 + ((wc * 32 + llo) << 7);      // B low base

    // prologue
    stA(0, 0); stA(0, 1); stB(0, 0); stB(0, 1);
    stA(0, 2); stA(0, 3); stB(0, 2); stB(0, 3);
    asm volatile("s_waitcnt vmcnt(4)" ::: "memory");  // Alo0,Blo0 done
    __builtin_amdgcn_s_barrier();
    bf16x8 A0[4][2], A1[4][2], B0[2][2], B1[2][2];
    {
        const char* sm0 = (const char*)smem;
#pragma unroll
        for (int m = 0; m < 4; ++m) {
            A0[m][0] = *(const bf16x8*)(sm0 + aoff + m * 2048 + kp0);
            A0[m][1] = *(const bf16x8*)(sm0 + aoff + m * 2048 + kp1);
        }
#pragma unroll
        for (int n = 0; n < 2; ++n) {
            B0[n][0] = *(const bf16x8*)(sm0 + boff + n * 2048 + kp0);
            B0[n][1] = *(const bf16x8*)(sm0 + boff + n * 2048 + kp1);
        }
    }
    asm volatile("s_waitcnt vmcnt(2)" ::: "memory");  // Ahi0 done (for ph1's A1)
    __builtin_amdgcn_s_barrier();

#pragma unroll 1
    for (int t = 0; t < 64; ++t) {
        const char* smc = (const char*)smem + (t & 1) * 65536;        // current
        const char* smn = (const char*)smem + (((t + 1) & 1)) * 65536; // next
        // ---- ph1: issue A1(8); stage Alo(t+1); lgkm(8); Q00; vm(2); barrier ----
#pragma unroll
        for (int m = 0; m < 4; ++m) {
            A1[m][0] = *(const bf16x8*)(smc + aoff + 16384 + m * 2048 + kp0);
            A1[m][1] = *(const bf16x8*)(smc + aoff + 16384 + m * 2048 + kp1);
        }
        if (t < 63) { stA(t + 1, 0); stA(t + 1, 1); }
        asm volatile("s_waitcnt lgkmcnt(8)" ::: "memory");
        __builtin_amdgcn_sched_barrier(0);
        __builtin_amdgcn_s_setprio(1);
#pragma unroll
        for (int ks = 0; ks < 2; ++ks)
#pragma unroll
            for (int m = 0; m < 4; ++m)
#pragma unroll
                for (int n = 0; n < 2; ++n)
                    acc[m][n] = __builtin_amdgcn_mfma_f32_16x16x32_bf16(A0[m][ks], B0[n][ks], acc[m][n], 0, 0, 0);
        __builtin_amdgcn_s_setprio(0);
        asm volatile("s_waitcnt vmcnt(2)" ::: "memory");
        __builtin_amdgcn_s_barrier();
        // ---- ph2: issue B1(4); stage Blo(t+1); lgkm(4); Q10 (no barrier) ----
#pragma unroll
        for (int n = 0; n < 2; ++n) {
            B1[n][0] = *(const bf16x8*)(smc + boff + 16384 + n * 2048 + kp0);
            B1[n][1] = *(const bf16x8*)(smc + boff + 16384 + n * 2048 + kp1);
        }
        if (t < 63) { stB(t + 1, 0); stB(t + 1, 1); }
        asm volatile("s_waitcnt lgkmcnt(4)" ::: "memory");
        __builtin_amdgcn_sched_barrier(0);
        __builtin_amdgcn_s_setprio(1);
#pragma unroll
        for (int ks = 0; ks < 2; ++ks)
#pragma unroll
            for (int m = 0; m < 4; ++m)
#pragma unroll
                for (int n = 0; n < 2; ++n)
                    acc[4 + m][n] = __builtin_amdgcn_mfma_f32_16x16x32_bf16(A1[m][ks], B0[n][ks], acc[4 + m][n], 0, 0, 0);
        __builtin_amdgcn_s_setprio(0);
        // ---- ph3: stage Ahi(t+1); lgkm(0); Q01; vm(2); barrier ----
        if (t < 63) { stA(t + 1, 2); stA(t + 1, 3); }
        asm volatile("s_waitcnt lgkmcnt(0)" ::: "memory");
        __builtin_amdgcn_sched_barrier(0);
        __builtin_amdgcn_s_setprio(1);
#pragma unroll
        for (int ks = 0; ks < 2; ++ks)
#pragma unroll
            for (int m = 0; m < 4; ++m)
#pragma unroll
                for (int n = 0; n < 2; ++n)
                    acc[m][2 + n] = __builtin_amdgcn_mfma_f32_16x16x32_bf16(A0[m][ks], B1[n][ks], acc[m][2 + n], 0, 0, 0);
        __builtin_amdgcn_s_setprio(0);
        asm volatile("s_waitcnt vmcnt(2)" ::: "memory");
        __builtin_amdgcn_s_barrier();
        // ---- ph4: issue A0,B0(t+1)(12); stage Bhi(t+1); Q11; vm(2); barrier ----
        if (t < 63) {
#pragma unroll
            for (int m = 0; m < 4; ++m) {
                A0[m][0] = *(const bf16x8*)(smn + aoff + m * 2048 + kp0);
                A0[m][1] = *(const bf16x8*)(smn + aoff + m * 2048 + kp1);
            }
#pragma unroll
            for (int n = 0; n < 2; ++n) {
                B0[n][0] = *(const bf16x8*)(smn + boff + n * 2048 + kp0);
                B0[n][1] = *(const bf16x8*)(smn + boff + n * 2048 + kp1);
            }
            stB(t + 1, 2); stB(t + 1, 3);
        }
        __builtin_amdgcn_sched_barrier(0);          // pin issue before MFMA
        __builtin_amdgcn_s_setprio(1);
#pragma unroll
        for (int ks = 0; ks < 2; ++ks)
#pragma unroll
            for (int m = 0; m < 4; ++m)
#pragma unroll
                for (int n = 0; n < 2; ++n)
                    acc[4 + m][2 + n] = __builtin_amdgcn_mfma_f32_16x16x32_bf16(A1[m][ks], B1[n][ks], acc[4 + m][2 + n], 0, 0, 0);
        __builtin_amdgcn_s_setprio(0);
        asm volatile("s_waitcnt vmcnt(2)" ::: "memory");
        __builtin_amdgcn_s_barrier();
    }

    // ---- epilogue: transposed Wht store + fused s1/s2 (2 eh per block) ----
    float* red = (float*)smem;                      // 1024 floats, LDS reuse
    red[tid] = 0.f;
    red[tid + 512] = 0.f;
    float w1v[4], w2v[4];
#pragma unroll
    for (int n = 0; n < 4; ++n) {
        int eh = tn * 2 + (n >> 1);
        int o = wc * 32 + (n & 1) * 16 + llo;
        w1v[n] = a1w[eh * 128 + o];
        w2v[n] = a2w[eh * 128 + o];
    }
    __syncthreads();
#pragma unroll
    for (int mi = 0; mi < 8; ++mi) {
        int R = (mi >> 2) * 128 + wr * 64 + (mi & 3) * 16 + lhi * 4;
#pragma unroll
        for (int n = 0; n < 4; ++n) {
            int eh = tn * 2 + (n >> 1);
            int o = wc * 32 + (n & 1) * 16 + llo;
            ushort4 pk;
            pk.x = f2bf(acc[mi][n][0]);
            pk.y = f2bf(acc[mi][n][1]);
            pk.z = f2bf(acc[mi][n][2]);
            pk.w = f2bf(acc[mi][n][3]);
            *(ushort4*)(Wht + ((((size_t)eh * 16 + tm) * 128 + o) * 256 + R)) = pk;
        }
#pragma unroll
        for (int r = 0; r < 4; ++r) {
            float p10 = acc[mi][0][r] * w1v[0] + acc[mi][1][r] * w1v[1];
            float p11 = acc[mi][2][r] * w1v[2] + acc[mi][3][r] * w1v[3];
            float p20 = acc[mi][0][r] * w2v[0] + acc[mi][1][r] * w2v[1];
            float p21 = acc[mi][2][r] * w2v[2] + acc[mi][3][r] * w2v[3];
#pragma unroll
            for (int off = 1; off < 16; off <<= 1) {
                p10 += __shfl_xor(p10, off);
                p11 += __shfl_xor(p11, off);
                p20 += __shfl_xor(p20, off);
                p21 += __shfl_xor(p21, off);
            }
            if (llo == 0) {
                int row = R + r;
                atomicAdd(&red[row], p10);
                atomicAdd(&red[256 + row], p11);
                atomicAdd(&red[512 + row], p20);
                atomicAdd(&red[768 + row], p21);
            }
        }
    }
    __syncthreads();
    {
        int ehl = tid >> 8, row = tid & 255;
        int eh = tn * 2 + ehl;
        s1[eh * 4096 + tm * 256 + row] = red[ehl * 256 + row] + a1b[eh];
        s2[eh * 4096 + tm * 256 + row] = red[512 + ehl * 256 + row] + a2b[eh];
    }
}

// ---------------------------------------------------------------------------
// K6: column softmax stats, SINGLE PASS with analytic bound (shift-invariant:
// any bound >= max works; bound = leaky(s1max+s2)+8 covers |L|max for randn).
// Writes packed stat[m] = {s2, bound, cinv, 0}.
__global__ __launch_bounds__(256) void colsoft_kernel(const float* __restrict__ s1,
                                                      const float* __restrict__ s2,
                                                      const float* __restrict__ Le,
                                                      float4* __restrict__ stat) {
    int mt = blockIdx.x, b = blockIdx.y, e = blockIdx.z;
    int t = threadIdx.x;
    __shared__ float Lt[256 * 32];
    __shared__ float s1L[8 * 256];
#pragma unroll
    for (int i = 0; i < 8; ++i) s1L[i * 256 + t] = s1[(e * 8 + i) * 4096 + b * 256 + t];
    const float* Lb = Le + ((size_t)(e * 16 + b) * 256) * 256 + mt * 32;
#pragma unroll
    for (int j = 0; j < 8; ++j) {
        int f = t + 256 * j;
        int n = f >> 3, c4 = (f & 7) * 4;
        *(float4*)(Lt + n * 32 + c4) = *(const float4*)(Lb + (size_t)n * 256 + c4);
    }
    __syncthreads();
    int h = t >> 5, mm = t & 31;
    int m = mt * 32 + mm;
    float s2v = s2[(e * 8 + h) * 4096 + b * 256 + m];
    const float* s1p = s1L + h * 256;
    // s1max over 256: 8 per thread + shuffle over the 32-lane half-wave
    float s1max = -1e30f;
#pragma unroll
    for (int u = 0; u < 8; ++u) s1max = fmaxf(s1max, s1p[mm * 8 + u]);
#pragma unroll
    for (int off = 16; off; off >>= 1) s1max = fmaxf(s1max, __shfl_xor(s1max, off));
    float sm = s1max + s2v;
    float bound = (sm > 0.f ? sm : 0.2f * sm) + 8.0f;
    float sum = 0.f;
    for (int n = 0; n < 256; ++n) {
        float x = s1p[n] + s2v;
        x = x > 0.f ? x : 0.2f * x;
        x += Lt[n * 32 + mm];
        sum += __expf(x - bound);
    }
    float4 st = {s2v, bound, 1.0f / sum, 0.f};
    stat[(e * 8 + h) * 4096 + b * 256 + m] = st;
}

// ---------------------------------------------------------------------------
// K7: MFMA att-apply. Per (nt,b,eh): D[o][n] = sum_m Wht[o][m]*att[n][m]
// L loads software-pipelined: iter k+1's 4 float4s issue before iter k's MFMA.
// LAST=0: st1b bf16 elu; LAST=1: h2 bf16 (no elu)
template <int LAST>
__global__ __launch_bounds__(256) void att_mfma_kernel(const float* __restrict__ s1,
                                                       const float4* __restrict__ stat,
                                                       const float* __restrict__ Le,
                                                       const bf16* __restrict__ Wht,
                                                       const float* __restrict__ sb,
                                                       bf16* __restrict__ outb) {
    int nt = blockIdx.x;   // 0..1
    int b = blockIdx.y;    // 0..15
    int eh = blockIdx.z;   // 0..31
    int e = eh >> 3;
    int tid = threadIdx.x;
    int w = tid >> 6, l = tid & 63;
    int q = l >> 4, mn = l & 15;
    __shared__ __align__(16) bf16 As[128 * 32];
    __shared__ __align__(16) bf16 Bs[128 * 40];   // att rows padded 32->40
    __shared__ float s1L[128];
    __shared__ __align__(16) float4 stL[256];

    int base = eh * 4096 + b * 256;
    if (tid < 128) s1L[tid] = s1[base + nt * 128 + tid];
    stL[tid] = stat[base + tid];
    __syncthreads();

    const bf16* Whtp = Wht + ((size_t)eh * 16 + b) * 32768;
    int nl = tid >> 1, mh = (tid & 1) * 16;
    const float* Lrow = Le + (((size_t)(e * 16 + b) * 256) + nt * 128 + nl) * 256;
    float s1v = s1L[nl];
    int srow = l >> 2;
    int sq = (l & 3) ^ ((l >> 3) & 3);
    int scol = sq * 8;
    int rsw = ((mn >> 1) & 3) << 3;

    f32x4 acc[4][4];
#pragma unroll
    for (int i = 0; i < 4; i++)
#pragma unroll
        for (int j = 0; j < 4; j++) acc[i][j] = (f32x4){0.f, 0.f, 0.f, 0.f};

    int wr = (w >> 1) * 64, wc = (w & 1) * 64;

    // prefetch L for iteration 0
    float4 lv[4];
#pragma unroll
    for (int jj = 0; jj < 4; ++jj) lv[jj] = *(const float4*)(Lrow + mh + jj * 4);

    for (int k0 = 0; k0 < 256; k0 += 32) {
#pragma unroll
        for (int u = 0; u < 2; ++u) {
            int i = 2 * w + u;
            gll16(Whtp + (size_t)(i * 16 + srow) * 256 + k0 + scol, (char*)As + i * 1024);
        }
        float4 cur[4];
#pragma unroll
        for (int jj = 0; jj < 4; ++jj) cur[jj] = lv[jj];
        if (k0 + 32 < 256) {
#pragma unroll
            for (int jj = 0; jj < 4; ++jj)
                lv[jj] = *(const float4*)(Lrow + k0 + 32 + mh + jj * 4);
        }
#pragma unroll
        for (int jj = 0; jj < 4; ++jj) {
            int mb = mh + jj * 4;
            float av[4];
#pragma unroll
            for (int c = 0; c < 4; ++c) {
                int m = k0 + mb + c;
                float4 stv = stL[m];
                float x = s1v + stv.x;
                x = x > 0.f ? x : 0.2f * x;
                x += ((const float*)&cur[jj])[c];
                av[c] = __expf(x - stv.y) * stv.z;
            }
            unsigned int u01 = (unsigned int)f2bf(av[0]) | ((unsigned int)f2bf(av[1]) << 16);
            unsigned int u23 = (unsigned int)f2bf(av[2]) | ((unsigned int)f2bf(av[3]) << 16);
            unsigned int* bp = (unsigned int*)Bs + (nl * 40 + mb) / 2;
            bp[0] = u01;
            bp[1] = u23;
        }
        __syncthreads();
        bf16x8 af[4], bfr[4];
#pragma unroll
        for (int i = 0; i < 4; ++i) {
            af[i]  = *(const bf16x8*)(As + (wr + i * 16 + mn) * 32 + ((q << 3) ^ rsw));
            bfr[i] = *(const bf16x8*)(Bs + (wc + i * 16 + mn) * 40 + q * 8);
        }
#pragma unroll
        for (int i = 0; i < 4; ++i)
#pragma unroll
            for (int j = 0; j < 4; ++j)
                acc[i][j] = __builtin_amdgcn_mfma_f32_16x16x32_bf16(af[i], bfr[j], acc[i][j], 0, 0, 0);
        __syncthreads();
    }
#pragma unroll
    for (int i = 0; i < 4; ++i) {
        int o0 = wr + i * 16 + q * 4;
        float4 sbv = *(const float4*)(sb + eh * 128 + o0);
#pragma unroll
        for (int j = 0; j < 4; ++j) {
            int n = wc + j * 16 + mn;
            float v0 = acc[i][j][0] + sbv.x;
            float v1 = acc[i][j][1] + sbv.y;
            float v2 = acc[i][j][2] + sbv.z;
            float v3 = acc[i][j][3] + sbv.w;
            if (LAST == 0) {
                v0 = v0 > 0.f ? v0 : __expf(v0) - 1.f;
                v1 = v1 > 0.f ? v1 : __expf(v1) - 1.f;
                v2 = v2 > 0.f ? v2 : __expf(v2) - 1.f;
                v3 = v3 > 0.f ? v3 : __expf(v3) - 1.f;
                ushort4 pk = {f2bf(v0), f2bf(v1), f2bf(v2), f2bf(v3)};
                *(ushort4*)(outb + (size_t)(b * 256 + nt * 128 + n) * 4096 + eh * Dq + o0) = pk;
            } else {
                ushort4 pk = {f2bf(v0), f2bf(v1), f2bf(v2), f2bf(v3)};
                *(ushort4*)(outb + ((size_t)eh * 4096 + b * 256 + nt * 128 + n) * Dq + o0) = pk;
            }
        }
    }
}

// ---------------------------------------------------------------------------
// K8: fused: st2[bn,o] = (1/32)*sum_eh h2b[eh,bn,o]; aw[bn] = sigmoid(st2.attW+attb)
__global__ __launch_bounds__(256) void reduce_aw_kernel(const bf16* __restrict__ h2b,
                                                        const float* __restrict__ attW,
                                                        const float* __restrict__ attb,
                                                        float* __restrict__ st2,
                                                        float* __restrict__ aw) {
    int t = threadIdx.x;
    int rl = t >> 7, o = t & 127;
    int r = blockIdx.x * 2 + rl;
    float acc = 0.f;
#pragma unroll
    for (int eh = 0; eh < EH; ++eh)
        acc += __bfloat162float(h2b[((size_t)eh * 4096 + r) * 128 + o]);
    acc *= (1.0f / 32.0f);
    st2[(size_t)r * 128 + o] = acc;
    float p = acc * attW[o];
#pragma unroll
    for (int off = 32; off; off >>= 1) p += __shfl_down(p, off);
    __shared__ float part[4];
    if ((t & 63) == 0) part[t >> 6] = p;
    __syncthreads();
    if (t == 0) aw[r] = 1.0f / (1.0f + __expf(-(part[0] + part[1] + attb[0])));
    if (t == 128) aw[r] = 1.0f / (1.0f + __expf(-(part[2] + part[3] + attb[0])));
}

// ---------------------------------------------------------------------------
// K10: out[b,d] = (1/256) * ( sum_o z[b,o]*outW[o,d] + sumaw[b]*outb[d] )
__global__ __launch_bounds__(128) void final_kernel(const float* __restrict__ st2,
                                                    const float* __restrict__ aw,
                                                    const float* __restrict__ outW,
                                                    const float* __restrict__ outb,
                                                    float* __restrict__ out) {
    int b = blockIdx.x;
    int t = threadIdx.x;
    __shared__ float awL[256], zL[128];
    awL[t] = aw[b * 256 + t];
    awL[t + 128] = aw[b * 256 + t + 128];
    __syncthreads();
    float z = 0.f;
    for (int n = 0; n < 256; ++n) z += awL[n] * st2[(size_t)(b * 256 + n) * Dq + t];
    float sa = 0.f;
    for (int n = 0; n < 256; ++n) sa += awL[n];
    zL[t] = z;
    __syncthreads();
    float acc = sa * outb[t];
    for (int o = 0; o < Dq; ++o) acc += zL[o] * outW[o * Dq + t];
    out[b * Dq + t] = acc * (1.0f / 256.0f);
}

// ---------------------------------------------------------------------------
extern "C" void kernel_launch(void* const* d_in, const int* in_sizes, int n_in,
                              void* d_out, int out_size, void* d_ws, size_t ws_size,
                              hipStream_t stream) {
    const int* nf = (const int*)d_in[0];
    const float* L = (const float*)d_in[1];
    const float* emb = (const float*)d_in[2];
    const float* W0 = (const float*)d_in[3];
    const float* W1 = (const float*)d_in[4];
    const float* a1w0 = (const float*)d_in[5];
    const float* a1b0 = (const float*)d_in[6];
    const float* a2w0 = (const float*)d_in[7];
    const float* a2b0 = (const float*)d_in[8];
    const float* a1w1 = (const float*)d_in[9];
    const float* a1b1 = (const float*)d_in[10];
    const float* a2w1 = (const float*)d_in[11];
    const float* a2b1 = (const float*)d_in[12];
    const float* sb0 = (const float*)d_in[13];
    const float* sb1 = (const float*)d_in[14];
    const float* outW = (const float*)d_in[15];
    const float* outb = (const float*)d_in[16];
    const float* attW = (const float*)d_in[17];
    const float* attb = (const float*)d_in[18];

    char* p = (char*)d_ws;
    bf16* st0b = (bf16*)(p);                        // [0, 1M)
    bf16* W0T  = (bf16*)(p + 1048576);              // [1M, 2M)
    bf16* W1T  = (bf16*)(p + 2097152);              // [2M, 34M)   dead after gemm1
    bf16* st1b = (bf16*)(p + 35651584);             // [34M, 66M)  dead after gemm1
    bf16* h2b  = (bf16*)(p + 2097152);              // [2M, 34M)   written by att1
    float* Le  = (float*)(p + 69206016);            // [66M, 82M)
    bf16* Wht  = (bf16*)(p + 85983232);             // [82M, 114M)
    float* s1  = (float*)(p + 119537664);           // 512K
    float* s2  = (float*)(p + 120061952);           // 512K
    float4* stat = (float4*)(p + 120586240);        // 2M
    float* st2 = (float*)(p);                       // reuse st0b/W0T (2 MB)
    float* aw  = s1;                                // reuse
    float* outp = (float*)d_out;

    prep_kernel<<<10368, 256, 0, stream>>>(nf, emb, W0, W1, L, st0b, W0T, W1T, Le);

    mfma_gemm_kernel<<<1024, 256, 0, stream>>>(st0b, W0T, Wht, a1w0, a1b0, a2w0, a2b0, s1, s2, 128);
    colsoft_kernel<<<dim3(8, 16, 4), 256, 0, stream>>>(s1, s2, Le, stat);
    att_mfma_kernel<0><<<dim3(2, 16, 32), 256, 0, stream>>>(s1, stat, Le, Wht, sb0, st1b);

    gemm4k_kernel<<<256, 512, 0, stream>>>(st1b, W1T, Wht, a1w1, a1b1, a2w1, a2b1, s1, s2);
    colsoft_kernel<<<dim3(8, 16, 4), 256, 0, stream>>>(s1, s2, Le, stat);
    att_mfma_kernel<1><<<dim3(2, 16, 32), 256, 0, stream>>>(s1, stat, Le, Wht, sb1, h2b);

    reduce_aw_kernel<<<2048, 256, 0, stream>>>(h2b, attW, attb, st2, aw);
    final_kernel<<<16, 128, 0, stream>>>(st2, aw, outW, outb, outp);
}